// Round 1
// baseline (3163.280 us; speedup 1.0000x reference)
//
#include <hip/hip_runtime.h>
#include <math.h>

// ---------------- problem constants ----------------
#define G_    32
#define NPG_  128
#define D_    128
#define N_    4096          // G_*NPG_
#define E_    65536
#define ND_   (N_*D_)       // 524288

// ---------------- workspace layout (float offsets, per side) ----------------
// per-side stride SS_; side s base = ws + s*SS_
#define W_OFF     0                     // E_ edge weights w
#define DEG_OFF   65536                 // N_ degrees (atomic, zeroed)
#define STATS_OFF 69632                 // 2048 floats of stats (zeroed):
//   [0:128) edge colsum  [128:256) edge colsumsq [256:384) alpha [384] beta
//   [512..1024) bn1: sum/ssq/scale/shift   [1024..1536) bn2: same
#define BUF0      71680
#define HL_OFF    (BUF0 + 0*ND_)        // h_local (bern output)
#define HA_OFF    (BUF0 + 1*ND_)        // mamba out (scattered); later x2
#define X1_OFF    (BUF0 + 2*ND_)        // pre-bn1 sum; later h2 (post-attn)
#define HMID_OFF  (BUF0 + 3*ND_)        // post-bn1
#define XC_OFF    (BUF0 + 4*ND_)        // conv output; later q
#define DTB_OFF   (BUF0 + 5*ND_)        // dt; later k
#define YB_OFF    (BUF0 + 6*ND_)        // scan y; later v
#define XZ_OFF    (BUF0 + 7*ND_)        // 2*ND_: [xq|z] per row (256); gt overwrites xq; later ffh
#define DBL_OFF   (BUF0 + 9*ND_)        // N_*40
#define TMP_OFF   (DBL_OFF + N_*40)     // 5*ND_ bern tmps[1..5]
#define SS_       ((size_t)(TMP_OFF + 5*ND_))   // 7,575,552 floats = 30.3 MB/side

__device__ __forceinline__ float leakyf(float x){ return x >= 0.f ? x : 0.02f*x; }
__device__ __forceinline__ float siluf (float x){ return x / (1.f + expf(-x)); }

// ---------------- edge feature helper ----------------
__device__ __forceinline__ void edge_feat(const float* __restrict__ x,
                                          const float* __restrict__ he,
                                          const int* __restrict__ ei,
                                          int e, float* feat, int& sN, int& dN)
{
  sN = ei[e]; dN = ei[E_ + e];
  float dx = x[sN*3+0]-x[dN*3+0];
  float dy = x[sN*3+1]-x[dN*3+1];
  float dz = x[sN*3+2]-x[dN*3+2];
  float d2 = dx*dx + dy*dy + dz*dz;
  feat[0] = expf(-d2/1.f);
  feat[1] = expf(-d2/10.f);
  feat[2] = expf(-d2/100.f);
  feat[3] = expf(-d2/1000.f);
  feat[4] = expf(-d2/10000.f);
#pragma unroll
  for (int j = 0; j < 27; ++j) feat[5+j] = he[(size_t)e*27 + j];
}

// ---------------- E1: per-column stats of t = leaky(feat@w1+b1) over E edges ----------------
__global__ __launch_bounds__(256)
void edge_stats_kernel(const float* __restrict__ xl, const float* __restrict__ xr,
                       const float* __restrict__ hel, const float* __restrict__ her,
                       const int* __restrict__ ei1, const int* __restrict__ ei2,
                       const float* __restrict__ w1, const float* __restrict__ b1,
                       float* __restrict__ ws)
{
  int side = blockIdx.y;
  const float* x  = side ? xr  : xl;
  const float* he = side ? her : hel;
  const int*   ei = side ? ei2 : ei1;
  float* stats = ws + (size_t)side*SS_ + STATS_OFF;
  __shared__ float w1l[4096];
  __shared__ float b1l[128];
  __shared__ float csum[128], cssq[128];
  int tid = threadIdx.x;
  for (int i = tid; i < 4096; i += 256) w1l[i] = w1[i];
  if (tid < 128) { b1l[tid] = b1[tid]; csum[tid] = 0.f; cssq[tid] = 0.f; }
  __syncthreads();
  int e = blockIdx.x*256 + tid;
  int sN, dN; float feat[32];
  edge_feat(x, he, ei, e, feat, sN, dN);
  int lane = tid & 63;
  for (int c = 0; c < 128; ++c) {
    float acc = b1l[c];
#pragma unroll
    for (int j = 0; j < 32; ++j) acc += feat[j]*w1l[j*128 + c];
    float t = leakyf(acc);
    float p1 = t, p2 = t*t;
#pragma unroll
    for (int off = 32; off; off >>= 1) { p1 += __shfl_xor(p1, off); p2 += __shfl_xor(p2, off); }
    if (lane == 0) { atomicAdd(&csum[c], p1); atomicAdd(&cssq[c], p2); }
  }
  __syncthreads();
  if (tid < 128) { atomicAdd(&stats[tid], csum[tid]); atomicAdd(&stats[128+tid], cssq[tid]); }
}

// ---------------- E2: finalize edge bn folded with emlp_w2 -> alpha,beta ----------------
__global__ void edge_finalize_kernel(const float* __restrict__ g_, const float* __restrict__ b_,
                                     const float* __restrict__ w2, const float* __restrict__ b2,
                                     float* __restrict__ ws)
{
  int side = blockIdx.y;
  float* stats = ws + (size_t)side*SS_ + STATS_OFF;
  __shared__ float red[128];
  int c = threadIdx.x;  // 128 threads
  const float invE = 1.f/(float)E_;
  float mean = stats[c]*invE;
  float var  = fmaxf(stats[128+c]*invE - mean*mean, 0.f);
  float scale = rsqrtf(var + 1e-5f) * g_[c];
  stats[256+c] = scale * w2[c];
  red[c] = (b_[c] - mean*scale) * w2[c];
  __syncthreads();
  for (int off = 64; off; off >>= 1) { if (c < off) red[c] += red[c+off]; __syncthreads(); }
  if (c == 0) stats[384] = red[0] + b2[0];
}

// ---------------- E3: w_e = relu(sum_c t_c*alpha_c + beta); deg = segsum(w, src) ----------------
__global__ __launch_bounds__(256)
void edge_w_kernel(const float* __restrict__ xl, const float* __restrict__ xr,
                   const float* __restrict__ hel, const float* __restrict__ her,
                   const int* __restrict__ ei1, const int* __restrict__ ei2,
                   const float* __restrict__ w1, const float* __restrict__ b1,
                   float* __restrict__ ws)
{
  int side = blockIdx.y;
  const float* x  = side ? xr  : xl;
  const float* he = side ? her : hel;
  const int*   ei = side ? ei2 : ei1;
  float* base = ws + (size_t)side*SS_;
  const float* stats = base + STATS_OFF;
  float* wbuf = base + W_OFF;
  float* deg  = base + DEG_OFF;
  __shared__ float w1l[4096];
  __shared__ float b1l[128], all_[128];
  int tid = threadIdx.x;
  for (int i = tid; i < 4096; i += 256) w1l[i] = w1[i];
  if (tid < 128) { b1l[tid] = b1[tid]; all_[tid] = stats[256+tid]; }
  __syncthreads();
  int e = blockIdx.x*256 + tid;
  int sN, dN; float feat[32];
  edge_feat(x, he, ei, e, feat, sN, dN);
  float accw = stats[384];
  for (int c = 0; c < 128; ++c) {
    float acc = b1l[c];
#pragma unroll
    for (int j = 0; j < 32; ++j) acc += feat[j]*w1l[j*128 + c];
    accw += leakyf(acc)*all_[c];
  }
  float w = fmaxf(accw, 0.f);
  wbuf[e] = w;
  atomicAdd(&deg[sN], w);
}

// ---------------- fused Bernstein propagation: all 27 SpMVs in one kernel ----------------
// grid (G_*8, 2): block = (group, 16-dim slice). LDS-resident 128x16 slices.
__global__ __launch_bounds__(256)
void bern_kernel(const float* __restrict__ hl_in, const float* __restrict__ hr_in,
                 const int* __restrict__ ei1, const int* __restrict__ ei2,
                 const float* __restrict__ bern_temp, float* __restrict__ ws)
{
  int side = blockIdx.y;
  int g  = blockIdx.x >> 3;
  int d0 = (blockIdx.x & 7) * 16;
  const float* h  = side ? hr_in : hl_in;
  const int*   ei = side ? ei2 : ei1;
  float* base = ws + (size_t)side*SS_;
  const float* wbuf = base + W_OFF;
  const float* deg  = base + DEG_OFF;
  float* tmpg = base + TMP_OFF;
  float* hloc = base + HL_OFF;
  __shared__ float v[2048], t[2048], acc[2048];
  __shared__ int   esrc[2048], edst[2048];
  __shared__ float enw[2048];
  __shared__ float temp[7];
  int tid = threadIdx.x;
  if (tid < 7) temp[tid] = fmaxf(bern_temp[tid], 0.f);
  int ebase = g*2048;
  for (int i = tid; i < 2048; i += 256) {
    int e = ebase + i;
    int sN = ei[e], dN = ei[E_ + e];
    esrc[i] = sN - g*128;
    edst[i] = dN - g*128;
    float ds_ = deg[sN], dd_ = deg[dN];
    float a = ds_ > 0.f ? rsqrtf(ds_ + 1e-12f) : 0.f;
    float b = dd_ > 0.f ? rsqrtf(dd_ + 1e-12f) : 0.f;
    enw[i] = wbuf[e]*a*b;
  }
  for (int i = tid; i < 2048; i += 256) {
    int n = i >> 4, d = i & 15;
    v[i] = h[(size_t)(g*128+n)*128 + d0 + d];
  }
  __syncthreads();
  const float coef[7] = {1.f/64.f, 6.f/64.f, 15.f/64.f, 20.f/64.f, 15.f/64.f, 6.f/64.f, 1.f/64.f};
  int dd = tid & 15, eo = tid >> 4;
  // forward: xv <- xv + A xv, store tmps[1..5]; tmps[6] stays in v
  for (int k = 1; k <= 6; ++k) {
    for (int i = tid; i < 2048; i += 256) t[i] = 0.f;
    __syncthreads();
    for (int i = eo; i < 2048; i += 16)
      atomicAdd(&t[(edst[i]<<4) + dd], enw[i]*v[(esrc[i]<<4) + dd]);
    __syncthreads();
    for (int i = tid; i < 2048; i += 256) {
      float nv = v[i] + t[i];
      v[i] = nv;
      if (k <= 5) tmpg[(size_t)((k-1)*N_ + g*128 + (i>>4))*128 + d0 + (i&15)] = nv;
    }
    __syncthreads();
  }
  for (int i = tid; i < 2048; i += 256) acc[i] = coef[0]*temp[0]*v[i];
  // backward: (I-A)^(bi+1) on tmps[5-bi]
  for (int bi = 0; bi < 6; ++bi) {
    __syncthreads();
    int kk = 5 - bi;
    for (int i = tid; i < 2048; i += 256) {
      int n = i >> 4, d = i & 15;
      v[i] = (kk == 0) ? h[(size_t)(g*128+n)*128 + d0 + d]
                       : tmpg[(size_t)((kk-1)*N_ + g*128 + n)*128 + d0 + d];
    }
    __syncthreads();
    for (int r = 0; r <= bi; ++r) {
      for (int i = tid; i < 2048; i += 256) t[i] = 0.f;
      __syncthreads();
      for (int i = eo; i < 2048; i += 16)
        atomicAdd(&t[(edst[i]<<4) + dd], enw[i]*v[(esrc[i]<<4) + dd]);
      __syncthreads();
      for (int i = tid; i < 2048; i += 256) v[i] -= t[i];
      __syncthreads();
    }
    float cf = coef[bi+1]*temp[bi+1];
    for (int i = tid; i < 2048; i += 256) acc[i] += cf*v[i];
  }
  __syncthreads();
  for (int i = tid; i < 2048; i += 256) {
    int n = i >> 4, d = i & 15;
    hloc[(size_t)(g*128+n)*128 + d0 + d] = acc[i];
  }
}

// ---------------- generic f32 GEMM: C = act(A[M x K] @ W[K x NC] (+bias)) (+addsrc) ----------------
// A rows optionally gathered (idx), C rows optionally scattered (idx). 32 rows/block.
template<int K, int NC, int TC, int ACT, int GATHER, int SCATTER, int ADDC, int BIAS>
__global__ __launch_bounds__(256)
void gemm_kernel(const float* __restrict__ A, int lda,
                 const float* __restrict__ W,
                 const float* __restrict__ bias,
                 float* __restrict__ C, int ldc,
                 const int* __restrict__ idx,
                 const float* __restrict__ addsrc)
{
  constexpr int RPT = TC/8;           // (256/TC) row-groups * RPT = 32 rows
  __shared__ float Alds[32][K];
  __shared__ float Wlds[K][TC];
  const int tid = threadIdx.x;
  const int r0 = blockIdx.x * 32;
  for (int i = tid; i < 32*K; i += 256) {
    int r = i / K, k = i % K;
    int row = GATHER ? idx[r0 + r] : (r0 + r);
    Alds[r][k] = A[(size_t)row*lda + k];
  }
  for (int c0 = 0; c0 < NC; c0 += TC) {
    __syncthreads();
    for (int i = tid; i < K*TC; i += 256) {
      int k = i / TC, c = i % TC;
      Wlds[k][c] = (c0 + c < NC) ? W[k*NC + c0 + c] : 0.f;
    }
    __syncthreads();
    const int cl = tid % TC;
    const int rsub = (tid / TC) * RPT;
    float accv[RPT];
#pragma unroll
    for (int j = 0; j < RPT; ++j) accv[j] = 0.f;
    for (int k = 0; k < K; ++k) {
      float wv = Wlds[k][cl];
#pragma unroll
      for (int j = 0; j < RPT; ++j) accv[j] += Alds[rsub+j][k]*wv;
    }
    int c = c0 + cl;
    if (c < NC) {
#pragma unroll
      for (int j = 0; j < RPT; ++j) {
        int row  = r0 + rsub + j;
        int orow = SCATTER ? idx[row] : row;
        float vv = accv[j];
        if (BIAS)     vv += bias[c];
        if (ACT == 1) vv = leakyf(vv);
        if (ACT == 2) vv = fmaxf(vv, 0.f);
        if (ADDC)     vv += addsrc[(size_t)orow*ldc + c];
        C[(size_t)orow*ldc + c] = vv;
      }
    }
  }
}

// ---------------- mamba: causal depthwise conv (DCONV=4) + silu ----------------
__global__ __launch_bounds__(256)
void conv_kernel(const float* __restrict__ cw, const float* __restrict__ cb, float* __restrict__ ws)
{
  int side = blockIdx.y;
  float* base = ws + (size_t)side*SS_;
  const float* xz = base + XZ_OFF;
  float* xc = base + XC_OFF;
  int i = blockIdx.x*256 + threadIdx.x;      // j*128+d
  int j = i >> 7, d = i & 127;
  int l = j & 127;
  float a = cb[d];
#pragma unroll
  for (int k = 0; k < 4; ++k) {
    int ll = l - 3 + k;
    if (ll >= 0) a += xz[(size_t)(j-3+k)*256 + d] * cw[d*4 + k];
  }
  xc[i] = siluf(a);
}

// ---------------- mamba: dt = softplus(dbl[:,:8] @ dt_w + dt_b) ----------------
__global__ __launch_bounds__(256)
void dt_kernel(const float* __restrict__ dtw, const float* __restrict__ dtbias, float* __restrict__ ws)
{
  int side = blockIdx.y;
  float* base = ws + (size_t)side*SS_;
  const float* dbl = base + DBL_OFF;
  float* dtb = base + DTB_OFF;
  int i = blockIdx.x*256 + threadIdx.x;
  int j = i >> 7, c = i & 127;
  float a = dtbias[c];
#pragma unroll
  for (int k = 0; k < 8; ++k) a += dbl[(size_t)j*40 + k]*dtw[k*128 + c];
  dtb[i] = a > 20.f ? a : log1pf(expf(a));
}

// ---------------- mamba: selective scan; thread = (b,d,s), shuffle-reduce over s=16 ----------------
__global__ __launch_bounds__(256)
void scan_kernel(const float* __restrict__ A_log, const float* __restrict__ Dp, float* __restrict__ ws)
{
  int side = blockIdx.y;
  float* base = ws + (size_t)side*SS_;
  const float* dtb = base + DTB_OFF;
  const float* xcb = base + XC_OFF;
  const float* dbl = base + DBL_OFF;
  float* yb = base + YB_OFF;
  int idx = blockIdx.x*256 + threadIdx.x;
  int s = idx & 15;
  int d = (idx >> 4) & 127;
  int b = idx >> 11;
  float Ac  = -expf(A_log[d*16 + s]);
  float dpv = Dp[d];
  float hsv = 0.f;
  for (int l = 0; l < 128; ++l) {
    int j = (b << 7) + l;
    float dtv = dtb[(size_t)j*128 + d];
    float xcv = xcb[(size_t)j*128 + d];
    float Bv  = dbl[(size_t)j*40 + 8 + s];
    float Cv  = dbl[(size_t)j*40 + 24 + s];
    hsv = expf(dtv*Ac)*hsv + dtv*Bv*xcv;
    float val = hsv*Cv;
    val += __shfl_xor(val, 1, 16);
    val += __shfl_xor(val, 2, 16);
    val += __shfl_xor(val, 4, 16);
    val += __shfl_xor(val, 8, 16);
    if (s == 0) yb[(size_t)j*128 + d] = val + xcv*dpv;
  }
}

// ---------------- mamba: gate gt = y * silu(z), written into xq region of xz ----------------
__global__ __launch_bounds__(256)
void gate_kernel(float* __restrict__ ws)
{
  int side = blockIdx.y;
  float* base = ws + (size_t)side*SS_;
  float* xz = base + XZ_OFF;
  const float* yb = base + YB_OFF;
  int i = blockIdx.x*256 + threadIdx.x;
  int j = i >> 7, d = i & 127;
  float z = xz[(size_t)j*256 + 128 + d];
  xz[(size_t)j*256 + d] = yb[i] * siluf(z);
}

// ---------------- column stats (optionally fused x1 = h + h_local + ha) ----------------
__global__ __launch_bounds__(256)
void stats_kernel(const float* __restrict__ hl_in, const float* __restrict__ hr_in,
                  float* __restrict__ ws, int mode, int statsoff)
{
  int side = blockIdx.y;
  float* base = ws + (size_t)side*SS_;
  const float* h    = side ? hr_in : hl_in;
  const float* hloc = base + HL_OFF;
  const float* ha   = base + HA_OFF;
  float* x1 = base + X1_OFF;
  float* stats = base + STATS_OFF + statsoff;
  int tid = threadIdx.x;
  int c = tid & 127;
  float s1 = 0.f, s2 = 0.f;
  for (int it = 0; it < 16; ++it) {
    int r = blockIdx.x*32 + (tid >> 7) + it*2;
    size_t i = (size_t)r*128 + c;
    float v;
    if (mode == 0) { v = h[i] + hloc[i] + ha[i]; x1[i] = v; }
    else           { v = ha[i]; }
    s1 += v; s2 += v*v;
  }
  __shared__ float red[256];
  red[tid] = s1; __syncthreads();
  if (tid < 128) atomicAdd(&stats[tid], red[tid] + red[tid+128]);
  __syncthreads();
  red[tid] = s2; __syncthreads();
  if (tid < 128) atomicAdd(&stats[128+tid], red[tid] + red[tid+128]);
}

__global__ void bn_finalize_kernel(const float* __restrict__ g_, const float* __restrict__ b_,
                                   float* __restrict__ ws, int statsoff, float invM)
{
  int side = blockIdx.y;
  float* stats = ws + (size_t)side*SS_ + STATS_OFF + statsoff;
  int c = threadIdx.x;   // 128 threads
  float mean = stats[c]*invM;
  float var  = fmaxf(stats[128+c]*invM - mean*mean, 0.f);
  float scale = rsqrtf(var + 1e-5f) * g_[c];
  stats[256+c] = scale;
  stats[384+c] = b_[c] - mean*scale;
}

__global__ __launch_bounds__(256)
void bn_apply_kernel(float* __restrict__ ws, float* __restrict__ dout,
                     int srcoff, int dstoff, int statsoff, int to_dout)
{
  int side = blockIdx.y;
  float* base = ws + (size_t)side*SS_;
  const float* src = base + srcoff;
  const float* stats = base + STATS_OFF + statsoff;
  float* dst = to_dout ? (dout + (size_t)side*ND_) : (base + dstoff);
  size_t i = (size_t)blockIdx.x*256 + threadIdx.x;
  int c = (int)(i & 127);
  dst[i] = src[i]*stats[256+c] + stats[384+c];
}

// ---------------- cross attention: block = (group, 32-row tile, direction) ----------------
__global__ __launch_bounds__(256)
void attn_kernel(float* __restrict__ ws)
{
  int dir = blockIdx.z;          // 0: q=side0 kv=side1 ; 1: q=side1 kv=side0
  int g   = blockIdx.x;
  int rt  = blockIdx.y;          // row tile 0..3
  float* baseq = ws + (size_t)dir*SS_;
  float* basek = ws + (size_t)(1-dir)*SS_;
  const float* qb = baseq + XC_OFF;
  const float* kb = basek + DTB_OFF;
  const float* vb = basek + YB_OFF;
  const float* hm = baseq + HMID_OFF;
  float* h2 = baseq + X1_OFF;
  __shared__ float kT[128*129];   // k transposed [d][n], pad 129; reused as v [n][d]
  __shared__ float sp[32*128];    // probabilities for this row tile
  int tid = threadIdx.x;
  for (int i = tid; i < 16384; i += 256) {
    int n = i >> 7, d = i & 127;
    kT[d*129 + n] = kb[(size_t)(g*128+n)*128 + d];
  }
  __syncthreads();
  int wv = tid >> 6, lane = tid & 63;
  for (int rl = wv; rl < 32; rl += 4) {
    int r = g*128 + rt*32 + rl;
    const float* qrow = qb + (size_t)r*128;
    float a0 = 0.f, a1 = 0.f;
    for (int d = 0; d < 128; ++d) {
      float qv = qrow[d];
      a0 += qv * kT[d*129 + lane];
      a1 += qv * kT[d*129 + 64 + lane];
    }
    float m = fmaxf(a0, a1);
#pragma unroll
    for (int off = 32; off; off >>= 1) m = fmaxf(m, __shfl_xor(m, off));
    float p0 = expf(a0 - m), p1 = expf(a1 - m);
    float ssum = p0 + p1;
#pragma unroll
    for (int off = 32; off; off >>= 1) ssum += __shfl_xor(ssum, off);
    float inv = 1.f/ssum;
    sp[rl*128 + lane]      = p0*inv;
    sp[rl*128 + 64 + lane] = p1*inv;
  }
  __syncthreads();
  for (int i = tid; i < 16384; i += 256) {
    int n = i >> 7, d = i & 127;
    kT[n*129 + d] = vb[(size_t)(g*128+n)*128 + d];
  }
  __syncthreads();
  for (int rl = wv; rl < 32; rl += 4) {
    int r = g*128 + rt*32 + rl;
    float a0 = 0.f, a1 = 0.f;
    const float* prow = sp + rl*128;
    for (int c = 0; c < 128; ++c) {
      float p = prow[c];
      a0 += p * kT[c*129 + lane];
      a1 += p * kT[c*129 + 64 + lane];
    }
    size_t o = (size_t)r*128;
    h2[o + lane]      = hm[o + lane]      + a0;
    h2[o + 64 + lane] = hm[o + 64 + lane] + a1;
  }
}

// ---------------- launch ----------------
extern "C" void kernel_launch(void* const* d_in, const int* in_sizes, int n_in,
                              void* d_out, int out_size, void* d_ws, size_t ws_size,
                              hipStream_t stream)
{
  const float* h_lig     = (const float*)d_in[0];
  const float* h_rec     = (const float*)d_in[1];
  const float* x_lig     = (const float*)d_in[2];
  const float* x_rec     = (const float*)d_in[3];
  const float* he_1      = (const float*)d_in[4];
  const float* he_2      = (const float*)d_in[5];
  const float* emlp_w1   = (const float*)d_in[6];
  const float* emlp_b1   = (const float*)d_in[7];
  const float* emlp_bn_g = (const float*)d_in[8];
  const float* emlp_bn_b = (const float*)d_in[9];
  const float* emlp_w2   = (const float*)d_in[10];
  const float* emlp_b2   = (const float*)d_in[11];
  const float* bern_temp = (const float*)d_in[12];
  const float* m_in_w    = (const float*)d_in[13];
  const float* m_conv_w  = (const float*)d_in[14];
  const float* m_conv_b  = (const float*)d_in[15];
  const float* m_xproj_w = (const float*)d_in[16];
  const float* m_dt_w    = (const float*)d_in[17];
  const float* m_dt_b    = (const float*)d_in[18];
  const float* m_A_log   = (const float*)d_in[19];
  const float* m_D       = (const float*)d_in[20];
  const float* m_out_w   = (const float*)d_in[21];
  const float* q_w       = (const float*)d_in[22];
  const float* k_w       = (const float*)d_in[23];
  const float* v_w       = (const float*)d_in[24];
  const float* bn1_g     = (const float*)d_in[25];
  const float* bn1_b     = (const float*)d_in[26];
  const float* bn2_g     = (const float*)d_in[27];
  const float* bn2_b     = (const float*)d_in[28];
  const float* ff_w1     = (const float*)d_in[29];
  const float* ff_b1     = (const float*)d_in[30];
  const float* ff_w2     = (const float*)d_in[31];
  const float* ff_b2     = (const float*)d_in[32];
  const int*   ei1       = (const int*)d_in[33];
  const int*   ei2       = (const int*)d_in[34];
  const int*   perm1     = (const int*)d_in[37];
  const int*   perm2     = (const int*)d_in[38];

  float* ws   = (float*)d_ws;
  float* dout = (float*)d_out;

  // zero atomic-accumulated regions (deg + stats are contiguous)
  for (int s = 0; s < 2; ++s)
    hipMemsetAsync((char*)d_ws + ((size_t)s*SS_ + DEG_OFF)*sizeof(float), 0,
                   (N_ + 2048)*sizeof(float), stream);

  // edge weights
  edge_stats_kernel<<<dim3(256,2), 256, 0, stream>>>(x_lig,x_rec,he_1,he_2,ei1,ei2,emlp_w1,emlp_b1,ws);
  edge_finalize_kernel<<<dim3(1,2), 128, 0, stream>>>(emlp_bn_g,emlp_bn_b,emlp_w2,emlp_b2,ws);
  edge_w_kernel<<<dim3(256,2), 256, 0, stream>>>(x_lig,x_rec,he_1,he_2,ei1,ei2,emlp_w1,emlp_b1,ws);

  // bernstein propagation (both sides, all 27 SpMVs)
  bern_kernel<<<dim3(G_*8,2), 256, 0, stream>>>(h_lig,h_rec,ei1,ei2,bern_temp,ws);

  // mamba
  for (int s = 0; s < 2; ++s) {
    float* base = ws + (size_t)s*SS_;
    const float* h_in = s ? h_rec : h_lig;
    const int* perm   = s ? perm2 : perm1;
    gemm_kernel<128,256,64,0,1,0,0,0><<<128,256,0,stream>>>(h_in,128,m_in_w,nullptr,base+XZ_OFF,256,perm,nullptr);
  }
  conv_kernel<<<dim3(2048,2), 256, 0, stream>>>(m_conv_w,m_conv_b,ws);
  for (int s = 0; s < 2; ++s) {
    float* base = ws + (size_t)s*SS_;
    gemm_kernel<128,40,64,0,0,0,0,0><<<128,256,0,stream>>>(base+XC_OFF,128,m_xproj_w,nullptr,base+DBL_OFF,40,nullptr,nullptr);
  }
  dt_kernel<<<dim3(2048,2), 256, 0, stream>>>(m_dt_w,m_dt_b,ws);
  scan_kernel<<<dim3(256,2), 256, 0, stream>>>(m_A_log,m_D,ws);
  gate_kernel<<<dim3(2048,2), 256, 0, stream>>>(ws);
  for (int s = 0; s < 2; ++s) {
    float* base = ws + (size_t)s*SS_;
    const int* perm = s ? perm2 : perm1;
    gemm_kernel<128,128,64,0,0,1,0,0><<<128,256,0,stream>>>(base+XZ_OFF,256,m_out_w,nullptr,base+HA_OFF,128,perm,nullptr);
  }

  // bn1( h + h_local + ha )
  stats_kernel<<<dim3(128,2), 256, 0, stream>>>(h_lig,h_rec,ws,0,512);
  bn_finalize_kernel<<<dim3(1,2), 128, 0, stream>>>(bn1_g,bn1_b,ws,512,1.f/(float)N_);
  bn_apply_kernel<<<dim3(2048,2), 256, 0, stream>>>(ws,dout,X1_OFF,HMID_OFF,512,0);

  // q,k,v projections (q,k leaky)
  for (int s = 0; s < 2; ++s) {
    float* base = ws + (size_t)s*SS_;
    gemm_kernel<128,128,64,1,0,0,0,0><<<128,256,0,stream>>>(base+HMID_OFF,128,q_w,nullptr,base+XC_OFF,128,nullptr,nullptr);
    gemm_kernel<128,128,64,1,0,0,0,0><<<128,256,0,stream>>>(base+HMID_OFF,128,k_w,nullptr,base+DTB_OFF,128,nullptr,nullptr);
    gemm_kernel<128,128,64,0,0,0,0,0><<<128,256,0,stream>>>(base+HMID_OFF,128,v_w,nullptr,base+YB_OFF,128,nullptr,nullptr);
  }
  attn_kernel<<<dim3(32,4,2), 256, 0, stream>>>(ws);

  // ffn + bn2
  for (int s = 0; s < 2; ++s) {
    float* base = ws + (size_t)s*SS_;
    gemm_kernel<128,256,64,2,0,0,0,1><<<128,256,0,stream>>>(base+X1_OFF,128,ff_w1,ff_b1,base+XZ_OFF,256,nullptr,nullptr);
  }
  for (int s = 0; s < 2; ++s) {
    float* base = ws + (size_t)s*SS_;
    gemm_kernel<256,128,32,0,0,0,1,1><<<128,256,0,stream>>>(base+XZ_OFF,256,ff_w2,ff_b2,base+HA_OFF,128,nullptr,base+X1_OFF);
  }
  stats_kernel<<<dim3(128,2), 256, 0, stream>>>(h_lig,h_rec,ws,1,1024);
  bn_finalize_kernel<<<dim3(1,2), 128, 0, stream>>>(bn2_g,bn2_b,ws,1024,1.f/(float)N_);
  bn_apply_kernel<<<dim3(2048,2), 256, 0, stream>>>(ws,dout,HA_OFF,0,1024,1);
}

// Round 2
// 1133.166 us; speedup vs baseline: 2.7915x; 2.7915x over previous
//
#include <hip/hip_runtime.h>
#include <math.h>

// ---------------- problem constants ----------------
#define G_    32
#define NPG_  128
#define D_    128
#define N_    4096          // G_*NPG_
#define E_    65536
#define ND_   (N_*D_)       // 524288

// ---------------- workspace layout (float offsets, per side) ----------------
#define W_OFF     0                     // E_ edge weights w
#define DEG_OFF   65536                 // N_ degrees (atomic, zeroed)
#define STATS_OFF 69632                 // 2048 floats of stats (zeroed):
//   [0:128) edge colsum  [128:256) edge colsumsq [256:384) alpha [384] beta
//   [512..1024) bn1: sum/ssq/scale/shift   [1024..1536) bn2: same
#define BUF0      71680
#define HL_OFF    (BUF0 + 0*ND_)        // h_local (bern output)
#define HA_OFF    (BUF0 + 1*ND_)        // mamba out (scattered); later x2
#define X1_OFF    (BUF0 + 2*ND_)        // pre-bn1 sum; later h2 (post-attn)
#define HMID_OFF  (BUF0 + 3*ND_)        // post-bn1
#define XC_OFF    (BUF0 + 4*ND_)        // conv output; later q
#define DTB_OFF   (BUF0 + 5*ND_)        // dt; later k
#define YB_OFF    (BUF0 + 6*ND_)        // scan y; later v
#define XZ_OFF    (BUF0 + 7*ND_)        // 2*ND_: [xq|z] per row (256)
#define DBL_OFF   (BUF0 + 9*ND_)        // N_*40
#define TMP_OFF   (DBL_OFF + N_*40)     // 5*ND_ bern tmps[1..5]
#define SS_       ((size_t)(TMP_OFF + 5*ND_))   // 30.3 MB/side

__device__ __forceinline__ float leakyf(float x){ return x >= 0.f ? x : 0.02f*x; }
__device__ __forceinline__ float siluf (float x){ return x / (1.f + expf(-x)); }

// ---------------- edge feature helper ----------------
__device__ __forceinline__ void edge_feat(const float* __restrict__ x,
                                          const float* __restrict__ he,
                                          const int* __restrict__ ei,
                                          int e, float* feat, int& sN, int& dN)
{
  sN = ei[e]; dN = ei[E_ + e];
  float dx = x[sN*3+0]-x[dN*3+0];
  float dy = x[sN*3+1]-x[dN*3+1];
  float dz = x[sN*3+2]-x[dN*3+2];
  float d2 = dx*dx + dy*dy + dz*dz;
  feat[0] = expf(-d2/1.f);
  feat[1] = expf(-d2/10.f);
  feat[2] = expf(-d2/100.f);
  feat[3] = expf(-d2/1000.f);
  feat[4] = expf(-d2/10000.f);
#pragma unroll
  for (int j = 0; j < 27; ++j) feat[5+j] = he[(size_t)e*27 + j];
}

// ---------------- E1: per-column stats of t = leaky(feat@w1+b1) over E edges ----------------
__global__ __launch_bounds__(256)
void edge_stats_kernel(const float* __restrict__ xl, const float* __restrict__ xr,
                       const float* __restrict__ hel, const float* __restrict__ her,
                       const int* __restrict__ ei1, const int* __restrict__ ei2,
                       const float* __restrict__ w1, const float* __restrict__ b1,
                       float* __restrict__ ws)
{
  int side = blockIdx.y;
  const float* x  = side ? xr  : xl;
  const float* he = side ? her : hel;
  const int*   ei = side ? ei2 : ei1;
  float* stats = ws + (size_t)side*SS_ + STATS_OFF;
  __shared__ float w1l[4096];
  __shared__ float b1l[128];
  __shared__ float csum[128], cssq[128];
  int tid = threadIdx.x;
  for (int i = tid; i < 4096; i += 256) w1l[i] = w1[i];
  if (tid < 128) { b1l[tid] = b1[tid]; csum[tid] = 0.f; cssq[tid] = 0.f; }
  __syncthreads();
  int e = blockIdx.x*256 + tid;
  int sN, dN; float feat[32];
  edge_feat(x, he, ei, e, feat, sN, dN);
  int lane = tid & 63;
  for (int c = 0; c < 128; ++c) {
    float acc = b1l[c];
#pragma unroll
    for (int j = 0; j < 32; ++j) acc += feat[j]*w1l[j*128 + c];
    float t = leakyf(acc);
    float p1 = t, p2 = t*t;
#pragma unroll
    for (int off = 32; off; off >>= 1) { p1 += __shfl_xor(p1, off); p2 += __shfl_xor(p2, off); }
    if (lane == 0) { atomicAdd(&csum[c], p1); atomicAdd(&cssq[c], p2); }
  }
  __syncthreads();
  if (tid < 128) { atomicAdd(&stats[tid], csum[tid]); atomicAdd(&stats[128+tid], cssq[tid]); }
}

// ---------------- E2: finalize edge bn folded with emlp_w2 -> alpha,beta ----------------
__global__ void edge_finalize_kernel(const float* __restrict__ g_, const float* __restrict__ b_,
                                     const float* __restrict__ w2, const float* __restrict__ b2,
                                     float* __restrict__ ws)
{
  int side = blockIdx.y;
  float* stats = ws + (size_t)side*SS_ + STATS_OFF;
  __shared__ float red[128];
  int c = threadIdx.x;  // 128 threads
  const float invE = 1.f/(float)E_;
  float mean = stats[c]*invE;
  float var  = fmaxf(stats[128+c]*invE - mean*mean, 0.f);
  float scale = rsqrtf(var + 1e-5f) * g_[c];
  stats[256+c] = scale * w2[c];
  red[c] = (b_[c] - mean*scale) * w2[c];
  __syncthreads();
  for (int off = 64; off; off >>= 1) { if (c < off) red[c] += red[c+off]; __syncthreads(); }
  if (c == 0) stats[384] = red[0] + b2[0];
}

// ---------------- E3: w_e = relu(sum_c t_c*alpha_c + beta); deg = segsum(w, src) ----------------
__global__ __launch_bounds__(256)
void edge_w_kernel(const float* __restrict__ xl, const float* __restrict__ xr,
                   const float* __restrict__ hel, const float* __restrict__ her,
                   const int* __restrict__ ei1, const int* __restrict__ ei2,
                   const float* __restrict__ w1, const float* __restrict__ b1,
                   float* __restrict__ ws)
{
  int side = blockIdx.y;
  const float* x  = side ? xr  : xl;
  const float* he = side ? her : hel;
  const int*   ei = side ? ei2 : ei1;
  float* base = ws + (size_t)side*SS_;
  const float* stats = base + STATS_OFF;
  float* wbuf = base + W_OFF;
  float* deg  = base + DEG_OFF;
  __shared__ float w1l[4096];
  __shared__ float b1l[128], all_[128];
  int tid = threadIdx.x;
  for (int i = tid; i < 4096; i += 256) w1l[i] = w1[i];
  if (tid < 128) { b1l[tid] = b1[tid]; all_[tid] = stats[256+tid]; }
  __syncthreads();
  int e = blockIdx.x*256 + tid;
  int sN, dN; float feat[32];
  edge_feat(x, he, ei, e, feat, sN, dN);
  float accw = stats[384];
  for (int c = 0; c < 128; ++c) {
    float acc = b1l[c];
#pragma unroll
    for (int j = 0; j < 32; ++j) acc += feat[j]*w1l[j*128 + c];
    accw += leakyf(acc)*all_[c];
  }
  float w = fmaxf(accw, 0.f);
  wbuf[e] = w;
  atomicAdd(&deg[sN], w);
}

// ---------------- dense Bernstein propagation ----------------
// block = (group, 32-dim slice); dense normalized adjacency in LDS (64KB),
// 27 propagation steps as register-tiled dense LDS matmuls.
__global__ __launch_bounds__(256)
void bern_dense_kernel(const float* __restrict__ hl_in, const float* __restrict__ hr_in,
                       const int* __restrict__ ei1, const int* __restrict__ ei2,
                       const float* __restrict__ bern_temp, float* __restrict__ ws)
{
  int side = blockIdx.y;
  int g  = blockIdx.x >> 2;
  int d0 = (blockIdx.x & 3) * 32;
  const float* h  = side ? hr_in : hl_in;
  const int*   ei = side ? ei2 : ei1;
  float* base = ws + (size_t)side*SS_;
  const float* wbuf = base + W_OFF;
  const float* deg  = base + DEG_OFF;
  float* tmpg = base + TMP_OFF;
  float* hloc = base + HL_OFF;

  __shared__ float A[128*128];   // 64KB: A[dst][src]
  __shared__ float v[128*32];    // 16KB: v[node][dim]
  __shared__ float temp[7];

  int tid = threadIdx.x;
  if (tid < 7) temp[tid] = fmaxf(bern_temp[tid], 0.f);
  for (int i = tid; i < 16384; i += 256) A[i] = 0.f;
  __syncthreads();

  int ebase = g*2048, nbase = g*128;
  for (int i = tid; i < 2048; i += 256) {
    int e = ebase + i;
    int sN = ei[e], dN = ei[E_ + e];
    float ds_ = deg[sN], dd_ = deg[dN];
    float a = ds_ > 0.f ? rsqrtf(ds_ + 1e-12f) : 0.f;
    float b = dd_ > 0.f ? rsqrtf(dd_ + 1e-12f) : 0.f;
    atomicAdd(&A[(dN - nbase)*128 + (sN - nbase)], wbuf[e]*a*b);
  }

  const int d  = tid & 31;        // dim within slice
  const int ng = tid >> 5;        // row group: rows ng*16 .. ng*16+15
  float cur[16], t[16], acc[16];

  // v = x slice; cur = own rows
#pragma unroll
  for (int j = 0; j < 16; ++j) {
    cur[j] = h[(size_t)(nbase + ng*16 + j)*128 + d0 + d];
    v[(ng*16 + j)*32 + d] = cur[j];
  }
  __syncthreads();

  // t = A @ v (each thread: 16 rows x 1 dim), float4 A-row reads
#define MATMUL_T()                                                        \
  {                                                                       \
    _Pragma("unroll")                                                     \
    for (int j = 0; j < 16; ++j) t[j] = 0.f;                              \
    for (int m4 = 0; m4 < 32; ++m4) {                                     \
      float vv0 = v[(m4*4+0)*32 + d];                                     \
      float vv1 = v[(m4*4+1)*32 + d];                                     \
      float vv2 = v[(m4*4+2)*32 + d];                                     \
      float vv3 = v[(m4*4+3)*32 + d];                                     \
      _Pragma("unroll")                                                   \
      for (int j = 0; j < 16; ++j) {                                      \
        const float4 a4 = *(const float4*)&A[(ng*16+j)*128 + m4*4];       \
        t[j] += a4.x*vv0 + a4.y*vv1 + a4.z*vv2 + a4.w*vv3;                \
      }                                                                   \
    }                                                                     \
  }

  const float coef[7] = {1.f/64.f, 6.f/64.f, 15.f/64.f, 20.f/64.f, 15.f/64.f, 6.f/64.f, 1.f/64.f};

  // forward: xv <- xv + A xv; store tmps[1..5] to global; k=6 stays in cur
  for (int k = 1; k <= 6; ++k) {
    MATMUL_T();
#pragma unroll
    for (int j = 0; j < 16; ++j) cur[j] += t[j];
    __syncthreads();
#pragma unroll
    for (int j = 0; j < 16; ++j) v[(ng*16 + j)*32 + d] = cur[j];
    if (k <= 5) {
#pragma unroll
      for (int j = 0; j < 16; ++j)
        tmpg[(size_t)((k-1)*N_ + nbase + ng*16 + j)*128 + d0 + d] = cur[j];
    }
    __syncthreads();
  }
#pragma unroll
  for (int j = 0; j < 16; ++j) acc[j] = coef[0]*temp[0]*cur[j];

  // backward: (I - A)^(bi+1) applied to tmps[5-bi]
  for (int bi = 0; bi < 6; ++bi) {
    int kk = 5 - bi;
    __syncthreads();   // prior v readers done before overwrite
#pragma unroll
    for (int j = 0; j < 16; ++j) {
      cur[j] = (kk == 0) ? h[(size_t)(nbase + ng*16 + j)*128 + d0 + d]
                         : tmpg[(size_t)((kk-1)*N_ + nbase + ng*16 + j)*128 + d0 + d];
      v[(ng*16 + j)*32 + d] = cur[j];
    }
    __syncthreads();
    for (int r = 0; r <= bi; ++r) {
      MATMUL_T();
#pragma unroll
      for (int j = 0; j < 16; ++j) cur[j] -= t[j];
      if (r < bi) {
        __syncthreads();
#pragma unroll
        for (int j = 0; j < 16; ++j) v[(ng*16 + j)*32 + d] = cur[j];
        __syncthreads();
      }
    }
    float cf = coef[bi+1]*temp[bi+1];
#pragma unroll
    for (int j = 0; j < 16; ++j) acc[j] += cf*cur[j];
  }

#pragma unroll
  for (int j = 0; j < 16; ++j)
    hloc[(size_t)(nbase + ng*16 + j)*128 + d0 + d] = acc[j];
#undef MATMUL_T
}

// ---------------- generic f32 GEMM ----------------
template<int K, int NC, int TC, int ACT, int GATHER, int SCATTER, int ADDC, int BIAS>
__global__ __launch_bounds__(256)
void gemm_kernel(const float* __restrict__ A, int lda,
                 const float* __restrict__ W,
                 const float* __restrict__ bias,
                 float* __restrict__ C, int ldc,
                 const int* __restrict__ idx,
                 const float* __restrict__ addsrc)
{
  constexpr int RPT = TC/8;
  __shared__ float Alds[32][K];
  __shared__ float Wlds[K][TC];
  const int tid = threadIdx.x;
  const int r0 = blockIdx.x * 32;
  for (int i = tid; i < 32*K; i += 256) {
    int r = i / K, k = i % K;
    int row = GATHER ? idx[r0 + r] : (r0 + r);
    Alds[r][k] = A[(size_t)row*lda + k];
  }
  for (int c0 = 0; c0 < NC; c0 += TC) {
    __syncthreads();
    for (int i = tid; i < K*TC; i += 256) {
      int k = i / TC, c = i % TC;
      Wlds[k][c] = (c0 + c < NC) ? W[k*NC + c0 + c] : 0.f;
    }
    __syncthreads();
    const int cl = tid % TC;
    const int rsub = (tid / TC) * RPT;
    float accv[RPT];
#pragma unroll
    for (int j = 0; j < RPT; ++j) accv[j] = 0.f;
    for (int k = 0; k < K; ++k) {
      float wv = Wlds[k][cl];
#pragma unroll
      for (int j = 0; j < RPT; ++j) accv[j] += Alds[rsub+j][k]*wv;
    }
    int c = c0 + cl;
    if (c < NC) {
#pragma unroll
      for (int j = 0; j < RPT; ++j) {
        int row  = r0 + rsub + j;
        int orow = SCATTER ? idx[row] : row;
        float vv = accv[j];
        if (BIAS)     vv += bias[c];
        if (ACT == 1) vv = leakyf(vv);
        if (ACT == 2) vv = fmaxf(vv, 0.f);
        if (ADDC)     vv += addsrc[(size_t)orow*ldc + c];
        C[(size_t)orow*ldc + c] = vv;
      }
    }
  }
}

// ---------------- mamba: causal depthwise conv (DCONV=4) + silu ----------------
__global__ __launch_bounds__(256)
void conv_kernel(const float* __restrict__ cw, const float* __restrict__ cb, float* __restrict__ ws)
{
  int side = blockIdx.y;
  float* base = ws + (size_t)side*SS_;
  const float* xz = base + XZ_OFF;
  float* xc = base + XC_OFF;
  int i = blockIdx.x*256 + threadIdx.x;      // j*128+d
  int j = i >> 7, d = i & 127;
  int l = j & 127;
  float a = cb[d];
#pragma unroll
  for (int k = 0; k < 4; ++k) {
    int ll = l - 3 + k;
    if (ll >= 0) a += xz[(size_t)(j-3+k)*256 + d] * cw[d*4 + k];
  }
  xc[i] = siluf(a);
}

// ---------------- mamba: dt = softplus(dbl[:,:8] @ dt_w + dt_b) ----------------
__global__ __launch_bounds__(256)
void dt_kernel(const float* __restrict__ dtw, const float* __restrict__ dtbias, float* __restrict__ ws)
{
  int side = blockIdx.y;
  float* base = ws + (size_t)side*SS_;
  const float* dbl = base + DBL_OFF;
  float* dtb = base + DTB_OFF;
  int i = blockIdx.x*256 + threadIdx.x;
  int j = i >> 7, c = i & 127;
  float a = dtbias[c];
#pragma unroll
  for (int k = 0; k < 8; ++k) a += dbl[(size_t)j*40 + k]*dtw[k*128 + c];
  dtb[i] = a > 20.f ? a : log1pf(expf(a));
}

// ---------------- mamba: selective scan ----------------
__global__ __launch_bounds__(256)
void scan_kernel(const float* __restrict__ A_log, const float* __restrict__ Dp, float* __restrict__ ws)
{
  int side = blockIdx.y;
  float* base = ws + (size_t)side*SS_;
  const float* dtb = base + DTB_OFF;
  const float* xcb = base + XC_OFF;
  const float* dbl = base + DBL_OFF;
  float* yb = base + YB_OFF;
  int idx = blockIdx.x*256 + threadIdx.x;
  int s = idx & 15;
  int d = (idx >> 4) & 127;
  int b = idx >> 11;
  float Ac  = -expf(A_log[d*16 + s]);
  float dpv = Dp[d];
  float hsv = 0.f;
  for (int l = 0; l < 128; ++l) {
    int j = (b << 7) + l;
    float dtv = dtb[(size_t)j*128 + d];
    float xcv = xcb[(size_t)j*128 + d];
    float Bv  = dbl[(size_t)j*40 + 8 + s];
    float Cv  = dbl[(size_t)j*40 + 24 + s];
    hsv = expf(dtv*Ac)*hsv + dtv*Bv*xcv;
    float val = hsv*Cv;
    val += __shfl_xor(val, 1, 16);
    val += __shfl_xor(val, 2, 16);
    val += __shfl_xor(val, 4, 16);
    val += __shfl_xor(val, 8, 16);
    if (s == 0) yb[(size_t)j*128 + d] = val + xcv*dpv;
  }
}

// ---------------- mamba: gate ----------------
__global__ __launch_bounds__(256)
void gate_kernel(float* __restrict__ ws)
{
  int side = blockIdx.y;
  float* base = ws + (size_t)side*SS_;
  float* xz = base + XZ_OFF;
  const float* yb = base + YB_OFF;
  int i = blockIdx.x*256 + threadIdx.x;
  int j = i >> 7, d = i & 127;
  float z = xz[(size_t)j*256 + 128 + d];
  xz[(size_t)j*256 + d] = yb[i] * siluf(z);
}

// ---------------- column stats ----------------
__global__ __launch_bounds__(256)
void stats_kernel(const float* __restrict__ hl_in, const float* __restrict__ hr_in,
                  float* __restrict__ ws, int mode, int statsoff)
{
  int side = blockIdx.y;
  float* base = ws + (size_t)side*SS_;
  const float* h    = side ? hr_in : hl_in;
  const float* hloc = base + HL_OFF;
  const float* ha   = base + HA_OFF;
  float* x1 = base + X1_OFF;
  float* stats = base + STATS_OFF + statsoff;
  int tid = threadIdx.x;
  int c = tid & 127;
  float s1 = 0.f, s2 = 0.f;
  for (int it = 0; it < 16; ++it) {
    int r = blockIdx.x*32 + (tid >> 7) + it*2;
    size_t i = (size_t)r*128 + c;
    float v;
    if (mode == 0) { v = h[i] + hloc[i] + ha[i]; x1[i] = v; }
    else           { v = ha[i]; }
    s1 += v; s2 += v*v;
  }
  __shared__ float red[256];
  red[tid] = s1; __syncthreads();
  if (tid < 128) atomicAdd(&stats[tid], red[tid] + red[tid+128]);
  __syncthreads();
  red[tid] = s2; __syncthreads();
  if (tid < 128) atomicAdd(&stats[128+tid], red[tid] + red[tid+128]);
}

__global__ void bn_finalize_kernel(const float* __restrict__ g_, const float* __restrict__ b_,
                                   float* __restrict__ ws, int statsoff, float invM)
{
  int side = blockIdx.y;
  float* stats = ws + (size_t)side*SS_ + STATS_OFF + statsoff;
  int c = threadIdx.x;   // 128 threads
  float mean = stats[c]*invM;
  float var  = fmaxf(stats[128+c]*invM - mean*mean, 0.f);
  float scale = rsqrtf(var + 1e-5f) * g_[c];
  stats[256+c] = scale;
  stats[384+c] = b_[c] - mean*scale;
}

__global__ __launch_bounds__(256)
void bn_apply_kernel(float* __restrict__ ws, float* __restrict__ dout,
                     int srcoff, int dstoff, int statsoff, int to_dout)
{
  int side = blockIdx.y;
  float* base = ws + (size_t)side*SS_;
  const float* src = base + srcoff;
  const float* stats = base + STATS_OFF + statsoff;
  float* dst = to_dout ? (dout + (size_t)side*ND_) : (base + dstoff);
  size_t i = (size_t)blockIdx.x*256 + threadIdx.x;
  int c = (int)(i & 127);
  dst[i] = src[i]*stats[256+c] + stats[384+c];
}

// ---------------- cross attention ----------------
__global__ __launch_bounds__(256)
void attn_kernel(float* __restrict__ ws)
{
  int dir = blockIdx.z;
  int g   = blockIdx.x;
  int rt  = blockIdx.y;
  float* baseq = ws + (size_t)dir*SS_;
  float* basek = ws + (size_t)(1-dir)*SS_;
  const float* qb = baseq + XC_OFF;
  const float* kb = basek + DTB_OFF;
  const float* vb = basek + YB_OFF;
  const float* hm = baseq + HMID_OFF;
  float* h2 = baseq + X1_OFF;
  __shared__ float kT[128*129];
  __shared__ float sp[32*128];
  int tid = threadIdx.x;
  for (int i = tid; i < 16384; i += 256) {
    int n = i >> 7, d = i & 127;
    kT[d*129 + n] = kb[(size_t)(g*128+n)*128 + d];
  }
  __syncthreads();
  int wv = tid >> 6, lane = tid & 63;
  for (int rl = wv; rl < 32; rl += 4) {
    int r = g*128 + rt*32 + rl;
    const float* qrow = qb + (size_t)r*128;
    float a0 = 0.f, a1 = 0.f;
    for (int d = 0; d < 128; ++d) {
      float qv = qrow[d];
      a0 += qv * kT[d*129 + lane];
      a1 += qv * kT[d*129 + 64 + lane];
    }
    float m = fmaxf(a0, a1);
#pragma unroll
    for (int off = 32; off; off >>= 1) m = fmaxf(m, __shfl_xor(m, off));
    float p0 = expf(a0 - m), p1 = expf(a1 - m);
    float ssum = p0 + p1;
#pragma unroll
    for (int off = 32; off; off >>= 1) ssum += __shfl_xor(ssum, off);
    float inv = 1.f/ssum;
    sp[rl*128 + lane]      = p0*inv;
    sp[rl*128 + 64 + lane] = p1*inv;
  }
  __syncthreads();
  for (int i = tid; i < 16384; i += 256) {
    int n = i >> 7, d = i & 127;
    kT[n*129 + d] = vb[(size_t)(g*128+n)*128 + d];
  }
  __syncthreads();
  for (int rl = wv; rl < 32; rl += 4) {
    int r = g*128 + rt*32 + rl;
    float a0 = 0.f, a1 = 0.f;
    const float* prow = sp + rl*128;
    for (int c = 0; c < 128; ++c) {
      float p = prow[c];
      a0 += p * kT[c*129 + lane];
      a1 += p * kT[c*129 + 64 + lane];
    }
    size_t o = (size_t)r*128;
    h2[o + lane]      = hm[o + lane]      + a0;
    h2[o + 64 + lane] = hm[o + 64 + lane] + a1;
  }
}

// ---------------- launch ----------------
extern "C" void kernel_launch(void* const* d_in, const int* in_sizes, int n_in,
                              void* d_out, int out_size, void* d_ws, size_t ws_size,
                              hipStream_t stream)
{
  const float* h_lig     = (const float*)d_in[0];
  const float* h_rec     = (const float*)d_in[1];
  const float* x_lig     = (const float*)d_in[2];
  const float* x_rec     = (const float*)d_in[3];
  const float* he_1      = (const float*)d_in[4];
  const float* he_2      = (const float*)d_in[5];
  const float* emlp_w1   = (const float*)d_in[6];
  const float* emlp_b1   = (const float*)d_in[7];
  const float* emlp_bn_g = (const float*)d_in[8];
  const float* emlp_bn_b = (const float*)d_in[9];
  const float* emlp_w2   = (const float*)d_in[10];
  const float* emlp_b2   = (const float*)d_in[11];
  const float* bern_temp = (const float*)d_in[12];
  const float* m_in_w    = (const float*)d_in[13];
  const float* m_conv_w  = (const float*)d_in[14];
  const float* m_conv_b  = (const float*)d_in[15];
  const float* m_xproj_w = (const float*)d_in[16];
  const float* m_dt_w    = (const float*)d_in[17];
  const float* m_dt_b    = (const float*)d_in[18];
  const float* m_A_log   = (const float*)d_in[19];
  const float* m_D       = (const float*)d_in[20];
  const float* m_out_w   = (const float*)d_in[21];
  const float* q_w       = (const float*)d_in[22];
  const float* k_w       = (const float*)d_in[23];
  const float* v_w       = (const float*)d_in[24];
  const float* bn1_g     = (const float*)d_in[25];
  const float* bn1_b     = (const float*)d_in[26];
  const float* bn2_g     = (const float*)d_in[27];
  const float* bn2_b     = (const float*)d_in[28];
  const float* ff_w1     = (const float*)d_in[29];
  const float* ff_b1     = (const float*)d_in[30];
  const float* ff_w2     = (const float*)d_in[31];
  const float* ff_b2     = (const float*)d_in[32];
  const int*   ei1       = (const int*)d_in[33];
  const int*   ei2       = (const int*)d_in[34];
  const int*   perm1     = (const int*)d_in[37];
  const int*   perm2     = (const int*)d_in[38];

  float* ws   = (float*)d_ws;
  float* dout = (float*)d_out;

  for (int s = 0; s < 2; ++s)
    hipMemsetAsync((char*)d_ws + ((size_t)s*SS_ + DEG_OFF)*sizeof(float), 0,
                   (N_ + 2048)*sizeof(float), stream);

  // edge weights
  edge_stats_kernel<<<dim3(256,2), 256, 0, stream>>>(x_lig,x_rec,he_1,he_2,ei1,ei2,emlp_w1,emlp_b1,ws);
  edge_finalize_kernel<<<dim3(1,2), 128, 0, stream>>>(emlp_bn_g,emlp_bn_b,emlp_w2,emlp_b2,ws);
  edge_w_kernel<<<dim3(256,2), 256, 0, stream>>>(x_lig,x_rec,he_1,he_2,ei1,ei2,emlp_w1,emlp_b1,ws);

  // bernstein propagation (dense per-group adjacency)
  bern_dense_kernel<<<dim3(G_*4,2), 256, 0, stream>>>(h_lig,h_rec,ei1,ei2,bern_temp,ws);

  // mamba
  for (int s = 0; s < 2; ++s) {
    float* base = ws + (size_t)s*SS_;
    const float* h_in = s ? h_rec : h_lig;
    const int* perm   = s ? perm2 : perm1;
    gemm_kernel<128,256,64,0,1,0,0,0><<<128,256,0,stream>>>(h_in,128,m_in_w,nullptr,base+XZ_OFF,256,perm,nullptr);
  }
  conv_kernel<<<dim3(2048,2), 256, 0, stream>>>(m_conv_w,m_conv_b,ws);
  for (int s = 0; s < 2; ++s) {
    float* base = ws + (size_t)s*SS_;
    gemm_kernel<128,40,64,0,0,0,0,0><<<128,256,0,stream>>>(base+XC_OFF,128,m_xproj_w,nullptr,base+DBL_OFF,40,nullptr,nullptr);
  }
  dt_kernel<<<dim3(2048,2), 256, 0, stream>>>(m_dt_w,m_dt_b,ws);
  scan_kernel<<<dim3(256,2), 256, 0, stream>>>(m_A_log,m_D,ws);
  gate_kernel<<<dim3(2048,2), 256, 0, stream>>>(ws);
  for (int s = 0; s < 2; ++s) {
    float* base = ws + (size_t)s*SS_;
    const int* perm = s ? perm2 : perm1;
    gemm_kernel<128,128,64,0,0,1,0,0><<<128,256,0,stream>>>(base+XZ_OFF,256,m_out_w,nullptr,base+HA_OFF,128,perm,nullptr);
  }

  // bn1( h + h_local + ha )
  stats_kernel<<<dim3(128,2), 256, 0, stream>>>(h_lig,h_rec,ws,0,512);
  bn_finalize_kernel<<<dim3(1,2), 128, 0, stream>>>(bn1_g,bn1_b,ws,512,1.f/(float)N_);
  bn_apply_kernel<<<dim3(2048,2), 256, 0, stream>>>(ws,dout,X1_OFF,HMID_OFF,512,0);

  // q,k,v projections (q,k leaky)
  for (int s = 0; s < 2; ++s) {
    float* base = ws + (size_t)s*SS_;
    gemm_kernel<128,128,64,1,0,0,0,0><<<128,256,0,stream>>>(base+HMID_OFF,128,q_w,nullptr,base+XC_OFF,128,nullptr,nullptr);
    gemm_kernel<128,128,64,1,0,0,0,0><<<128,256,0,stream>>>(base+HMID_OFF,128,k_w,nullptr,base+DTB_OFF,128,nullptr,nullptr);
    gemm_kernel<128,128,64,0,0,0,0,0><<<128,256,0,stream>>>(base+HMID_OFF,128,v_w,nullptr,base+YB_OFF,128,nullptr,nullptr);
  }
  attn_kernel<<<dim3(32,4,2), 256, 0, stream>>>(ws);

  // ffn + bn2
  for (int s = 0; s < 2; ++s) {
    float* base = ws + (size_t)s*SS_;
    gemm_kernel<128,256,64,2,0,0,0,1><<<128,256,0,stream>>>(base+X1_OFF,128,ff_w1,ff_b1,base+XZ_OFF,256,nullptr,nullptr);
  }
  for (int s = 0; s < 2; ++s) {
    float* base = ws + (size_t)s*SS_;
    gemm_kernel<256,128,32,0,0,0,1,1><<<128,256,0,stream>>>(base+XZ_OFF,256,ff_w2,ff_b2,base+HA_OFF,128,nullptr,base+X1_OFF);
  }
  stats_kernel<<<dim3(128,2), 256, 0, stream>>>(h_lig,h_rec,ws,1,1024);
  bn_finalize_kernel<<<dim3(1,2), 128, 0, stream>>>(bn2_g,bn2_b,ws,1024,1.f/(float)N_);
  bn_apply_kernel<<<dim3(2048,2), 256, 0, stream>>>(ws,dout,HA_OFF,0,1024,1);
}

// Round 3
// 584.859 us; speedup vs baseline: 5.4086x; 1.9375x over previous
//
#include <hip/hip_runtime.h>
#include <math.h>

// ---------------- problem constants ----------------
#define G_    32
#define NPG_  128
#define D_    128
#define N_    4096          // G_*NPG_
#define E_    65536
#define ND_   (N_*D_)       // 524288

// ---------------- workspace layout (float offsets, per side) ----------------
#define W_OFF     0                     // E_ edge weights w
#define DEG_OFF   65536                 // N_ degrees (atomic, zeroed)
#define STATS_OFF 69632                 // 2048 floats of stats (zeroed):
//   [0:128) edge colsum  [128:256) edge colsumsq [256:384) alpha [384] beta
//   [512..1024) bn1: sum/ssq/scale/shift   [1024..1536) bn2: same
#define BUF0      71680
#define HL_OFF    (BUF0 + 0*ND_)        // h_local (bern output)
#define HA_OFF    (BUF0 + 1*ND_)        // mamba out (scattered); later x2
#define X1_OFF    (BUF0 + 2*ND_)        // pre-bn1 sum; later h2 (post-attn)
#define HMID_OFF  (BUF0 + 3*ND_)        // post-bn1
#define XC_OFF    (BUF0 + 4*ND_)        // conv output; later q
#define DTB_OFF   (BUF0 + 5*ND_)        // dt; later k
#define YB_OFF    (BUF0 + 6*ND_)        // scan y; later v
#define XZ_OFF    (BUF0 + 7*ND_)        // 2*ND_: [xq|z] per row (256)
#define DBL_OFF   (BUF0 + 9*ND_)        // N_*40
#define SS_       ((size_t)(DBL_OFF + N_*40))

__device__ __forceinline__ float leakyf(float x){ return x >= 0.f ? x : 0.02f*x; }
__device__ __forceinline__ float siluf (float x){ return x / (1.f + expf(-x)); }

// ---------------- edge feature helper ----------------
__device__ __forceinline__ void edge_feat(const float* __restrict__ x,
                                          const float* __restrict__ he,
                                          const int* __restrict__ ei,
                                          int e, float* feat, int& sN, int& dN)
{
  sN = ei[e]; dN = ei[E_ + e];
  float dx = x[sN*3+0]-x[dN*3+0];
  float dy = x[sN*3+1]-x[dN*3+1];
  float dz = x[sN*3+2]-x[dN*3+2];
  float d2 = dx*dx + dy*dy + dz*dz;
  feat[0] = expf(-d2/1.f);
  feat[1] = expf(-d2/10.f);
  feat[2] = expf(-d2/100.f);
  feat[3] = expf(-d2/1000.f);
  feat[4] = expf(-d2/10000.f);
#pragma unroll
  for (int j = 0; j < 27; ++j) feat[5+j] = he[(size_t)e*27 + j];
}

// ---------------- E1: per-column stats of t = leaky(feat@w1+b1) ----------------
// thread = (column, edge-half); w1 column in registers, feats staged in LDS.
__global__ __launch_bounds__(256)
void edge_stats_kernel(const float* __restrict__ xl, const float* __restrict__ xr,
                       const float* __restrict__ hel, const float* __restrict__ her,
                       const int* __restrict__ ei1, const int* __restrict__ ei2,
                       const float* __restrict__ w1, const float* __restrict__ b1,
                       float* __restrict__ ws)
{
  int side = blockIdx.y;
  const float* x  = side ? xr  : xl;
  const float* he = side ? her : hel;
  const int*   ei = side ? ei2 : ei1;
  float* stats = ws + (size_t)side*SS_ + STATS_OFF;
  __shared__ float featl[256*36];     // 36KB, pad 36 to spread write banks
  __shared__ float csum[2][128], cssq[2][128];
  int tid = threadIdx.x;
  {
    int sN, dN; float feat[32];
    edge_feat(x, he, ei, blockIdx.x*256 + tid, feat, sN, dN);
#pragma unroll
    for (int j4 = 0; j4 < 8; ++j4)
      *(float4*)&featl[tid*36 + j4*4] = *(float4*)&feat[j4*4];
  }
  int c = tid & 127, hh = tid >> 7;
  float w1c[32];
#pragma unroll
  for (int j = 0; j < 32; ++j) w1c[j] = w1[j*128 + c];
  float b1c = b1[c];
  __syncthreads();
  float s1 = 0.f, s2 = 0.f;
  for (int e = 0; e < 128; ++e) {
    const float* f = &featl[(hh*128 + e)*36];
    float acc = b1c;
#pragma unroll
    for (int j4 = 0; j4 < 8; ++j4) {
      float4 f4 = *(const float4*)&f[j4*4];
      acc += f4.x*w1c[j4*4] + f4.y*w1c[j4*4+1] + f4.z*w1c[j4*4+2] + f4.w*w1c[j4*4+3];
    }
    float t = leakyf(acc);
    s1 += t; s2 += t*t;
  }
  csum[hh][c] = s1; cssq[hh][c] = s2;
  __syncthreads();
  if (tid < 128) {
    atomicAdd(&stats[tid],     csum[0][tid] + csum[1][tid]);
    atomicAdd(&stats[128+tid], cssq[0][tid] + cssq[1][tid]);
  }
}

// ---------------- E2: finalize edge bn folded with emlp_w2 -> alpha,beta ----------------
__global__ void edge_finalize_kernel(const float* __restrict__ g_, const float* __restrict__ b_,
                                     const float* __restrict__ w2, const float* __restrict__ b2,
                                     float* __restrict__ ws)
{
  int side = blockIdx.y;
  float* stats = ws + (size_t)side*SS_ + STATS_OFF;
  __shared__ float red[128];
  int c = threadIdx.x;  // 128 threads
  const float invE = 1.f/(float)E_;
  float mean = stats[c]*invE;
  float var  = fmaxf(stats[128+c]*invE - mean*mean, 0.f);
  float scale = rsqrtf(var + 1e-5f) * g_[c];
  stats[256+c] = scale * w2[c];
  red[c] = (b_[c] - mean*scale) * w2[c];
  __syncthreads();
  for (int off = 64; off; off >>= 1) { if (c < off) red[c] += red[c+off]; __syncthreads(); }
  if (c == 0) stats[384] = red[0] + b2[0];
}

// ---------------- E3: w_e = relu(sum_c leaky(t_c)*alpha_c + beta); deg ----------------
// transposed w1 in LDS, float4 broadcast reads
__global__ __launch_bounds__(256)
void edge_w_kernel(const float* __restrict__ xl, const float* __restrict__ xr,
                   const float* __restrict__ hel, const float* __restrict__ her,
                   const int* __restrict__ ei1, const int* __restrict__ ei2,
                   const float* __restrict__ w1, const float* __restrict__ b1,
                   float* __restrict__ ws)
{
  int side = blockIdx.y;
  const float* x  = side ? xr  : xl;
  const float* he = side ? her : hel;
  const int*   ei = side ? ei2 : ei1;
  float* base = ws + (size_t)side*SS_;
  const float* stats = base + STATS_OFF;
  float* wbuf = base + W_OFF;
  float* deg  = base + DEG_OFF;
  __shared__ float w1t[128*32];       // transposed [c][j]
  __shared__ float b1l[128], all_[128];
  int tid = threadIdx.x;
  for (int i = tid; i < 4096; i += 256) {
    int j = i & 31, c = i >> 5;
    w1t[c*32 + j] = w1[j*128 + c];
  }
  if (tid < 128) { b1l[tid] = b1[tid]; all_[tid] = stats[256+tid]; }
  __syncthreads();
  int e = blockIdx.x*256 + tid;
  int sN, dN; float feat[32];
  edge_feat(x, he, ei, e, feat, sN, dN);
  float accw = stats[384];
  for (int c = 0; c < 128; ++c) {
    float acc = b1l[c];
#pragma unroll
    for (int j4 = 0; j4 < 8; ++j4) {
      float4 w4 = *(const float4*)&w1t[c*32 + j4*4];   // wave-broadcast
      acc += feat[j4*4]*w4.x + feat[j4*4+1]*w4.y + feat[j4*4+2]*w4.z + feat[j4*4+3]*w4.w;
    }
    accw += leakyf(acc)*all_[c];
  }
  float w = fmaxf(accw, 0.f);
  wbuf[e] = w;
  atomicAdd(&deg[sN], w);
}

// ---------------- Bernstein propagation via Horner on monomial expansion ----------------
// out = sum_m a_m A^m h, a from 7x7 integer basis table x temp. 6 matmuls.
// block = (group, 32-dim slice); A dense in LDS padded [128][132].
__global__ __launch_bounds__(256)
void bern_horner_kernel(const float* __restrict__ hl_in, const float* __restrict__ hr_in,
                        const int* __restrict__ ei1, const int* __restrict__ ei2,
                        const float* __restrict__ bern_temp, float* __restrict__ ws)
{
  int side = blockIdx.y;
  int g  = blockIdx.x >> 2;
  int d0 = (blockIdx.x & 3) * 32;
  const float* h  = side ? hr_in : hl_in;
  const int*   ei = side ? ei2 : ei1;
  float* base = ws + (size_t)side*SS_;
  const float* wbuf = base + W_OFF;
  const float* deg  = base + DEG_OFF;
  float* hloc = base + HL_OFF;

  __shared__ float A[128*132];   // 67.5KB padded: A[dst][src]
  __shared__ float v[128*32];    // 16KB: v[node][dim]
  int tid = threadIdx.x;
  for (int i = tid; i < 128*132; i += 256) A[i] = 0.f;

  // monomial coefficients: (1-x)^j (1+x)^(6-j) expansion table
  const float btab[7][7] = {
    { 1,  6, 15,  20, 15,  6,  1},
    { 1,  4,  5,   0, -5, -4, -1},
    { 1,  2, -1,  -4, -1,  2,  1},
    { 1,  0, -3,   0,  3,  0, -1},
    { 1, -2, -1,   4, -1, -2,  1},
    { 1, -4,  5,   0, -5,  4, -1},
    { 1, -6, 15, -20, 15, -6,  1}};
  const float comb6[7] = {1,6,15,20,15,6,1};
  float a[7];
#pragma unroll
  for (int m = 0; m < 7; ++m) a[m] = 0.f;
#pragma unroll
  for (int j = 0; j < 7; ++j) {
    float tj = fmaxf(bern_temp[j], 0.f) * comb6[j] * (1.f/64.f);
#pragma unroll
    for (int m = 0; m < 7; ++m) a[m] += tj * btab[j][m];
  }
  __syncthreads();

  int ebase = g*2048, nbase = g*128;
  for (int i = tid; i < 2048; i += 256) {
    int e = ebase + i;
    int sN = ei[e], dN = ei[E_ + e];
    float ds_ = deg[sN], dd_ = deg[dN];
    float aa = ds_ > 0.f ? rsqrtf(ds_ + 1e-12f) : 0.f;
    float bb = dd_ > 0.f ? rsqrtf(dd_ + 1e-12f) : 0.f;
    atomicAdd(&A[(dN - nbase)*132 + (sN - nbase)], wbuf[e]*aa*bb);
  }

  // thread tile: 4 rows x 4 dims
  const int db = (tid & 7)*4;
  const int rb = (tid >> 3)*4;
  float hreg[4][4], r[4][4], t[4][4];
#pragma unroll
  for (int i = 0; i < 4; ++i) {
    float4 h4 = *(const float4*)&h[(size_t)(nbase + rb + i)*128 + d0 + db];
    hreg[i][0]=h4.x; hreg[i][1]=h4.y; hreg[i][2]=h4.z; hreg[i][3]=h4.w;
#pragma unroll
    for (int jj = 0; jj < 4; ++jj) r[i][jj] = a[6]*hreg[i][jj];
  }

  for (int step = 5; step >= 0; --step) {
    __syncthreads();   // prior matmul reads done (and A-build on first iter)
#pragma unroll
    for (int i = 0; i < 4; ++i)
      *(float4*)&v[(rb+i)*32 + db] = make_float4(r[i][0], r[i][1], r[i][2], r[i][3]);
    __syncthreads();
#pragma unroll
    for (int i = 0; i < 4; ++i)
#pragma unroll
      for (int jj = 0; jj < 4; ++jj) t[i][jj] = 0.f;
    for (int k = 0; k < 128; k += 4) {
      float4 V0 = *(const float4*)&v[(k+0)*32 + db];
      float4 V1 = *(const float4*)&v[(k+1)*32 + db];
      float4 V2 = *(const float4*)&v[(k+2)*32 + db];
      float4 V3 = *(const float4*)&v[(k+3)*32 + db];
#pragma unroll
      for (int i = 0; i < 4; ++i) {
        float4 A4 = *(const float4*)&A[(rb+i)*132 + k];
        t[i][0] += A4.x*V0.x + A4.y*V1.x + A4.z*V2.x + A4.w*V3.x;
        t[i][1] += A4.x*V0.y + A4.y*V1.y + A4.z*V2.y + A4.w*V3.y;
        t[i][2] += A4.x*V0.z + A4.y*V1.z + A4.z*V2.z + A4.w*V3.z;
        t[i][3] += A4.x*V0.w + A4.y*V1.w + A4.z*V2.w + A4.w*V3.w;
      }
    }
    float ak = a[step];
#pragma unroll
    for (int i = 0; i < 4; ++i)
#pragma unroll
      for (int jj = 0; jj < 4; ++jj) r[i][jj] = t[i][jj] + ak*hreg[i][jj];
  }

#pragma unroll
  for (int i = 0; i < 4; ++i)
    *(float4*)&hloc[(size_t)(nbase + rb + i)*128 + d0 + db] =
        make_float4(r[i][0], r[i][1], r[i][2], r[i][3]);
}

// ---------------- generic f32 GEMM, grid.y = side ----------------
template<int K, int NC, int TC, int ACT, int GATHER, int SCATTER, int ADDC, int BIAS>
__global__ __launch_bounds__(256)
void gemm_kernel(const float* __restrict__ A0, const float* __restrict__ A1, int lda,
                 const float* __restrict__ W, const float* __restrict__ bias,
                 float* __restrict__ C0, float* __restrict__ C1, int ldc,
                 const int* __restrict__ idx0, const int* __restrict__ idx1,
                 const float* __restrict__ add0, const float* __restrict__ add1)
{
  int side = blockIdx.y;
  const float* A = side ? A1 : A0;
  float* C = side ? C1 : C0;
  const int* idx = side ? idx1 : idx0;
  const float* addsrc = side ? add1 : add0;
  constexpr int RPT = TC/8;
  __shared__ float Alds[32][K];
  __shared__ float Wlds[K][TC];
  const int tid = threadIdx.x;
  const int r0 = blockIdx.x * 32;
  for (int i = tid; i < 32*K; i += 256) {
    int r = i / K, k = i % K;
    int row = GATHER ? idx[r0 + r] : (r0 + r);
    Alds[r][k] = A[(size_t)row*lda + k];
  }
  for (int c0 = 0; c0 < NC; c0 += TC) {
    __syncthreads();
    for (int i = tid; i < K*TC; i += 256) {
      int k = i / TC, c = i % TC;
      Wlds[k][c] = (c0 + c < NC) ? W[k*NC + c0 + c] : 0.f;
    }
    __syncthreads();
    const int cl = tid % TC;
    const int rsub = (tid / TC) * RPT;
    float accv[RPT];
#pragma unroll
    for (int j = 0; j < RPT; ++j) accv[j] = 0.f;
    for (int k = 0; k < K; k += 4) {
      float w0 = Wlds[k][cl], w1v = Wlds[k+1][cl], w2v = Wlds[k+2][cl], w3v = Wlds[k+3][cl];
#pragma unroll
      for (int j = 0; j < RPT; ++j) {
        float4 a4 = *(const float4*)&Alds[rsub+j][k];   // wave-broadcast
        accv[j] += a4.x*w0 + a4.y*w1v + a4.z*w2v + a4.w*w3v;
      }
    }
    int c = c0 + cl;
    if (c < NC) {
#pragma unroll
      for (int j = 0; j < RPT; ++j) {
        int row  = r0 + rsub + j;
        int orow = SCATTER ? idx[row] : row;
        float vv = accv[j];
        if (BIAS)     vv += bias[c];
        if (ACT == 1) vv = leakyf(vv);
        if (ACT == 2) vv = fmaxf(vv, 0.f);
        if (ADDC)     vv += addsrc[(size_t)orow*ldc + c];
        C[(size_t)orow*ldc + c] = vv;
      }
    }
  }
}

// ---------------- mamba: causal depthwise conv (DCONV=4) + silu ----------------
__global__ __launch_bounds__(256)
void conv_kernel(const float* __restrict__ cw, const float* __restrict__ cb, float* __restrict__ ws)
{
  int side = blockIdx.y;
  float* base = ws + (size_t)side*SS_;
  const float* xz = base + XZ_OFF;
  float* xc = base + XC_OFF;
  int i = blockIdx.x*256 + threadIdx.x;      // j*128+d
  int j = i >> 7, d = i & 127;
  int l = j & 127;
  float a = cb[d];
#pragma unroll
  for (int k = 0; k < 4; ++k) {
    int ll = l - 3 + k;
    if (ll >= 0) a += xz[(size_t)(j-3+k)*256 + d] * cw[d*4 + k];
  }
  xc[i] = siluf(a);
}

// ---------------- mamba: dt = softplus(dbl[:,:8] @ dt_w + dt_b) ----------------
__global__ __launch_bounds__(256)
void dt_kernel(const float* __restrict__ dtw, const float* __restrict__ dtbias, float* __restrict__ ws)
{
  int side = blockIdx.y;
  float* base = ws + (size_t)side*SS_;
  const float* dbl = base + DBL_OFF;
  float* dtb = base + DTB_OFF;
  int i = blockIdx.x*256 + threadIdx.x;
  int j = i >> 7, c = i & 127;
  float a = dtbias[c];
#pragma unroll
  for (int k = 0; k < 8; ++k) a += dbl[(size_t)j*40 + k]*dtw[k*128 + c];
  dtb[i] = a > 20.f ? a : log1pf(expf(a));
}

// ---------------- mamba: selective scan ----------------
__global__ __launch_bounds__(256)
void scan_kernel(const float* __restrict__ A_log, const float* __restrict__ Dp, float* __restrict__ ws)
{
  int side = blockIdx.y;
  float* base = ws + (size_t)side*SS_;
  const float* dtb = base + DTB_OFF;
  const float* xcb = base + XC_OFF;
  const float* dbl = base + DBL_OFF;
  float* yb = base + YB_OFF;
  int idx = blockIdx.x*256 + threadIdx.x;
  int s = idx & 15;
  int d = (idx >> 4) & 127;
  int b = idx >> 11;
  float Ac  = -expf(A_log[d*16 + s]);
  float dpv = Dp[d];
  float hsv = 0.f;
  for (int l = 0; l < 128; ++l) {
    int j = (b << 7) + l;
    float dtv = dtb[(size_t)j*128 + d];
    float xcv = xcb[(size_t)j*128 + d];
    float Bv  = dbl[(size_t)j*40 + 8 + s];
    float Cv  = dbl[(size_t)j*40 + 24 + s];
    hsv = expf(dtv*Ac)*hsv + dtv*Bv*xcv;
    float val = hsv*Cv;
    val += __shfl_xor(val, 1, 16);
    val += __shfl_xor(val, 2, 16);
    val += __shfl_xor(val, 4, 16);
    val += __shfl_xor(val, 8, 16);
    if (s == 0) yb[(size_t)j*128 + d] = val + xcv*dpv;
  }
}

// ---------------- mamba: gate ----------------
__global__ __launch_bounds__(256)
void gate_kernel(float* __restrict__ ws)
{
  int side = blockIdx.y;
  float* base = ws + (size_t)side*SS_;
  float* xz = base + XZ_OFF;
  const float* yb = base + YB_OFF;
  int i = blockIdx.x*256 + threadIdx.x;
  int j = i >> 7, d = i & 127;
  float z = xz[(size_t)j*256 + 128 + d];
  xz[(size_t)j*256 + d] = yb[i] * siluf(z);
}

// ---------------- column stats ----------------
__global__ __launch_bounds__(256)
void stats_kernel(const float* __restrict__ hl_in, const float* __restrict__ hr_in,
                  float* __restrict__ ws, int mode, int statsoff)
{
  int side = blockIdx.y;
  float* base = ws + (size_t)side*SS_;
  const float* h    = side ? hr_in : hl_in;
  const float* hloc = base + HL_OFF;
  const float* ha   = base + HA_OFF;
  float* x1 = base + X1_OFF;
  float* stats = base + STATS_OFF + statsoff;
  int tid = threadIdx.x;
  int c = tid & 127;
  float s1 = 0.f, s2 = 0.f;
  for (int it = 0; it < 16; ++it) {
    int r = blockIdx.x*32 + (tid >> 7) + it*2;
    size_t i = (size_t)r*128 + c;
    float v;
    if (mode == 0) { v = h[i] + hloc[i] + ha[i]; x1[i] = v; }
    else           { v = ha[i]; }
    s1 += v; s2 += v*v;
  }
  __shared__ float red[256];
  red[tid] = s1; __syncthreads();
  if (tid < 128) atomicAdd(&stats[tid], red[tid] + red[tid+128]);
  __syncthreads();
  red[tid] = s2; __syncthreads();
  if (tid < 128) atomicAdd(&stats[128+tid], red[tid] + red[tid+128]);
}

__global__ void bn_finalize_kernel(const float* __restrict__ g_, const float* __restrict__ b_,
                                   float* __restrict__ ws, int statsoff, float invM)
{
  int side = blockIdx.y;
  float* stats = ws + (size_t)side*SS_ + STATS_OFF + statsoff;
  int c = threadIdx.x;   // 128 threads
  float mean = stats[c]*invM;
  float var  = fmaxf(stats[128+c]*invM - mean*mean, 0.f);
  float scale = rsqrtf(var + 1e-5f) * g_[c];
  stats[256+c] = scale;
  stats[384+c] = b_[c] - mean*scale;
}

__global__ __launch_bounds__(256)
void bn_apply_kernel(float* __restrict__ ws, float* __restrict__ dout,
                     int srcoff, int dstoff, int statsoff, int to_dout)
{
  int side = blockIdx.y;
  float* base = ws + (size_t)side*SS_;
  const float* src = base + srcoff;
  const float* stats = base + STATS_OFF + statsoff;
  float* dst = to_dout ? (dout + (size_t)side*ND_) : (base + dstoff);
  size_t i = (size_t)blockIdx.x*256 + threadIdx.x;
  int c = (int)(i & 127);
  dst[i] = src[i]*stats[256+c] + stats[384+c];
}

// ---------------- cross attention ----------------
__global__ __launch_bounds__(256)
void attn_kernel(float* __restrict__ ws)
{
  int dir = blockIdx.z;
  int g   = blockIdx.x;
  int rt  = blockIdx.y;
  float* baseq = ws + (size_t)dir*SS_;
  float* basek = ws + (size_t)(1-dir)*SS_;
  const float* qb = baseq + XC_OFF;
  const float* kb = basek + DTB_OFF;
  const float* vb = basek + YB_OFF;
  const float* hm = baseq + HMID_OFF;
  float* h2 = baseq + X1_OFF;
  __shared__ float kT[128*129];
  __shared__ float sp[32*128];
  int tid = threadIdx.x;
  for (int i = tid; i < 16384; i += 256) {
    int n = i >> 7, d = i & 127;
    kT[d*129 + n] = kb[(size_t)(g*128+n)*128 + d];
  }
  __syncthreads();
  int wv = tid >> 6, lane = tid & 63;
  for (int rl = wv; rl < 32; rl += 4) {
    int r = g*128 + rt*32 + rl;
    const float* qrow = qb + (size_t)r*128;
    float a0 = 0.f, a1 = 0.f;
    for (int d = 0; d < 128; ++d) {
      float qv = qrow[d];
      a0 += qv * kT[d*129 + lane];
      a1 += qv * kT[d*129 + 64 + lane];
    }
    float m = fmaxf(a0, a1);
#pragma unroll
    for (int off = 32; off; off >>= 1) m = fmaxf(m, __shfl_xor(m, off));
    float p0 = expf(a0 - m), p1 = expf(a1 - m);
    float ssum = p0 + p1;
#pragma unroll
    for (int off = 32; off; off >>= 1) ssum += __shfl_xor(ssum, off);
    float inv = 1.f/ssum;
    sp[rl*128 + lane]      = p0*inv;
    sp[rl*128 + 64 + lane] = p1*inv;
  }
  __syncthreads();
  for (int i = tid; i < 16384; i += 256) {
    int n = i >> 7, d = i & 127;
    kT[n*129 + d] = vb[(size_t)(g*128+n)*128 + d];
  }
  __syncthreads();
  for (int rl = wv; rl < 32; rl += 4) {
    int r = g*128 + rt*32 + rl;
    float a0 = 0.f, a1 = 0.f;
    const float* prow = sp + rl*128;
    for (int c = 0; c < 128; ++c) {
      float p = prow[c];
      a0 += p * kT[c*129 + lane];
      a1 += p * kT[c*129 + 64 + lane];
    }
    size_t o = (size_t)r*128;
    h2[o + lane]      = hm[o + lane]      + a0;
    h2[o + 64 + lane] = hm[o + 64 + lane] + a1;
  }
}

// ---------------- launch ----------------
extern "C" void kernel_launch(void* const* d_in, const int* in_sizes, int n_in,
                              void* d_out, int out_size, void* d_ws, size_t ws_size,
                              hipStream_t stream)
{
  const float* h_lig     = (const float*)d_in[0];
  const float* h_rec     = (const float*)d_in[1];
  const float* x_lig     = (const float*)d_in[2];
  const float* x_rec     = (const float*)d_in[3];
  const float* he_1      = (const float*)d_in[4];
  const float* he_2      = (const float*)d_in[5];
  const float* emlp_w1   = (const float*)d_in[6];
  const float* emlp_b1   = (const float*)d_in[7];
  const float* emlp_bn_g = (const float*)d_in[8];
  const float* emlp_bn_b = (const float*)d_in[9];
  const float* emlp_w2   = (const float*)d_in[10];
  const float* emlp_b2   = (const float*)d_in[11];
  const float* bern_temp = (const float*)d_in[12];
  const float* m_in_w    = (const float*)d_in[13];
  const float* m_conv_w  = (const float*)d_in[14];
  const float* m_conv_b  = (const float*)d_in[15];
  const float* m_xproj_w = (const float*)d_in[16];
  const float* m_dt_w    = (const float*)d_in[17];
  const float* m_dt_b    = (const float*)d_in[18];
  const float* m_A_log   = (const float*)d_in[19];
  const float* m_D       = (const float*)d_in[20];
  const float* m_out_w   = (const float*)d_in[21];
  const float* q_w       = (const float*)d_in[22];
  const float* k_w       = (const float*)d_in[23];
  const float* v_w       = (const float*)d_in[24];
  const float* bn1_g     = (const float*)d_in[25];
  const float* bn1_b     = (const float*)d_in[26];
  const float* bn2_g     = (const float*)d_in[27];
  const float* bn2_b     = (const float*)d_in[28];
  const float* ff_w1     = (const float*)d_in[29];
  const float* ff_b1     = (const float*)d_in[30];
  const float* ff_w2     = (const float*)d_in[31];
  const float* ff_b2     = (const float*)d_in[32];
  const int*   ei1       = (const int*)d_in[33];
  const int*   ei2       = (const int*)d_in[34];
  const int*   perm1     = (const int*)d_in[37];
  const int*   perm2     = (const int*)d_in[38];

  float* ws   = (float*)d_ws;
  float* dout = (float*)d_out;

#define B0(off) (ws + (size_t)(off))
#define B1(off) (ws + SS_ + (size_t)(off))

  for (int s = 0; s < 2; ++s)
    hipMemsetAsync((char*)d_ws + ((size_t)s*SS_ + DEG_OFF)*sizeof(float), 0,
                   (N_ + 2048)*sizeof(float), stream);

  // edge weights
  edge_stats_kernel<<<dim3(256,2), 256, 0, stream>>>(x_lig,x_rec,he_1,he_2,ei1,ei2,emlp_w1,emlp_b1,ws);
  edge_finalize_kernel<<<dim3(1,2), 128, 0, stream>>>(emlp_bn_g,emlp_bn_b,emlp_w2,emlp_b2,ws);
  edge_w_kernel<<<dim3(256,2), 256, 0, stream>>>(x_lig,x_rec,he_1,he_2,ei1,ei2,emlp_w1,emlp_b1,ws);

  // bernstein propagation (Horner, 6 matmuls)
  bern_horner_kernel<<<dim3(G_*4,2), 256, 0, stream>>>(h_lig,h_rec,ei1,ei2,bern_temp,ws);

  // mamba
  gemm_kernel<128,256,64,0,1,0,0,0><<<dim3(128,2),256,0,stream>>>(
      h_lig,h_rec,128, m_in_w,nullptr, B0(XZ_OFF),B1(XZ_OFF),256, perm1,perm2, nullptr,nullptr);
  conv_kernel<<<dim3(2048,2), 256, 0, stream>>>(m_conv_w,m_conv_b,ws);
  gemm_kernel<128,40,64,0,0,0,0,0><<<dim3(128,2),256,0,stream>>>(
      B0(XC_OFF),B1(XC_OFF),128, m_xproj_w,nullptr, B0(DBL_OFF),B1(DBL_OFF),40, nullptr,nullptr, nullptr,nullptr);
  dt_kernel<<<dim3(2048,2), 256, 0, stream>>>(m_dt_w,m_dt_b,ws);
  scan_kernel<<<dim3(256,2), 256, 0, stream>>>(m_A_log,m_D,ws);
  gate_kernel<<<dim3(2048,2), 256, 0, stream>>>(ws);
  gemm_kernel<128,128,64,0,0,1,0,0><<<dim3(128,2),256,0,stream>>>(
      B0(XZ_OFF),B1(XZ_OFF),256, m_out_w,nullptr, B0(HA_OFF),B1(HA_OFF),128, perm1,perm2, nullptr,nullptr);

  // bn1( h + h_local + ha )
  stats_kernel<<<dim3(128,2), 256, 0, stream>>>(h_lig,h_rec,ws,0,512);
  bn_finalize_kernel<<<dim3(1,2), 128, 0, stream>>>(bn1_g,bn1_b,ws,512,1.f/(float)N_);
  bn_apply_kernel<<<dim3(2048,2), 256, 0, stream>>>(ws,dout,X1_OFF,HMID_OFF,512,0);

  // q,k,v projections (q,k leaky)
  gemm_kernel<128,128,64,1,0,0,0,0><<<dim3(128,2),256,0,stream>>>(
      B0(HMID_OFF),B1(HMID_OFF),128, q_w,nullptr, B0(XC_OFF),B1(XC_OFF),128, nullptr,nullptr, nullptr,nullptr);
  gemm_kernel<128,128,64,1,0,0,0,0><<<dim3(128,2),256,0,stream>>>(
      B0(HMID_OFF),B1(HMID_OFF),128, k_w,nullptr, B0(DTB_OFF),B1(DTB_OFF),128, nullptr,nullptr, nullptr,nullptr);
  gemm_kernel<128,128,64,0,0,0,0,0><<<dim3(128,2),256,0,stream>>>(
      B0(HMID_OFF),B1(HMID_OFF),128, v_w,nullptr, B0(YB_OFF),B1(YB_OFF),128, nullptr,nullptr, nullptr,nullptr);
  attn_kernel<<<dim3(32,4,2), 256, 0, stream>>>(ws);

  // ffn + bn2
  gemm_kernel<128,256,64,2,0,0,0,1><<<dim3(128,2),256,0,stream>>>(
      B0(X1_OFF),B1(X1_OFF),128, ff_w1,ff_b1, B0(XZ_OFF),B1(XZ_OFF),256, nullptr,nullptr, nullptr,nullptr);
  gemm_kernel<256,128,32,0,0,0,1,1><<<dim3(128,2),256,0,stream>>>(
      B0(XZ_OFF),B1(XZ_OFF),256, ff_w2,ff_b2, B0(HA_OFF),B1(HA_OFF),128, nullptr,nullptr, B0(X1_OFF),B1(X1_OFF));
  stats_kernel<<<dim3(128,2), 256, 0, stream>>>(h_lig,h_rec,ws,1,1024);
  bn_finalize_kernel<<<dim3(1,2), 128, 0, stream>>>(bn2_g,bn2_b,ws,1024,1.f/(float)N_);
  bn_apply_kernel<<<dim3(2048,2), 256, 0, stream>>>(ws,dout,HA_OFF,0,1024,1);
}

// Round 4
// 482.133 us; speedup vs baseline: 6.5610x; 1.2131x over previous
//
#include <hip/hip_runtime.h>
#include <math.h>

// ---------------- problem constants ----------------
#define G_    32
#define NPG_  128
#define D_    128
#define N_    4096          // G_*NPG_
#define E_    65536
#define ND_   (N_*D_)       // 524288

// ---------------- workspace layout (float offsets, per side) ----------------
#define W_OFF     0                     // E_ edge weights w
#define DEG_OFF   65536                 // N_ degrees (atomic, zeroed)
#define STATS_OFF 69632                 // 2048 floats of stats (zeroed):
//   [0:128) edge colsum  [128:256) edge colsumsq [256:384) alpha [384] beta
//   [512..1024) bn1: sum/ssq/scale/shift   [1024..1536) bn2: same
#define BUF0      71680
#define HL_OFF    (BUF0 + 0*ND_)        // h_local (bern output)
#define HA_OFF    (BUF0 + 1*ND_)        // mamba out (scattered); later x2
#define X1_OFF    (BUF0 + 2*ND_)        // pre-bn1 sum; later h2 (post-attn)
#define HMID_OFF  (BUF0 + 3*ND_)        // post-bn1
#define XC_OFF    (BUF0 + 4*ND_)        // conv output; later q
#define DTB_OFF   (BUF0 + 5*ND_)        // k
#define YB_OFF    (BUF0 + 6*ND_)        // v
#define XZ_OFF    (BUF0 + 7*ND_)        // 2*ND_: [xq|z] per row (256); scan gate overwrites xq
#define DBL_OFF   (BUF0 + 9*ND_)        // N_*40
#define SS_       ((size_t)(DBL_OFF + N_*40))

__device__ __forceinline__ float leakyf(float x){ return x >= 0.f ? x : 0.02f*x; }
__device__ __forceinline__ float siluf (float x){ return x / (1.f + expf(-x)); }

// ---------------- edge feature helper ----------------
__device__ __forceinline__ void edge_feat(const float* __restrict__ x,
                                          const float* __restrict__ he,
                                          const int* __restrict__ ei,
                                          int e, float* feat, int& sN, int& dN)
{
  sN = ei[e]; dN = ei[E_ + e];
  float dx = x[sN*3+0]-x[dN*3+0];
  float dy = x[sN*3+1]-x[dN*3+1];
  float dz = x[sN*3+2]-x[dN*3+2];
  float d2 = dx*dx + dy*dy + dz*dz;
  feat[0] = expf(-d2/1.f);
  feat[1] = expf(-d2/10.f);
  feat[2] = expf(-d2/100.f);
  feat[3] = expf(-d2/1000.f);
  feat[4] = expf(-d2/10000.f);
#pragma unroll
  for (int j = 0; j < 27; ++j) feat[5+j] = he[(size_t)e*27 + j];
}

// ---------------- E1: per-column stats of t = leaky(feat@w1+b1) ----------------
__global__ __launch_bounds__(256)
void edge_stats_kernel(const float* __restrict__ xl, const float* __restrict__ xr,
                       const float* __restrict__ hel, const float* __restrict__ her,
                       const int* __restrict__ ei1, const int* __restrict__ ei2,
                       const float* __restrict__ w1, const float* __restrict__ b1,
                       float* __restrict__ ws)
{
  int side = blockIdx.y;
  const float* x  = side ? xr  : xl;
  const float* he = side ? her : hel;
  const int*   ei = side ? ei2 : ei1;
  float* stats = ws + (size_t)side*SS_ + STATS_OFF;
  __shared__ float featl[256*36];
  __shared__ float csum[2][128], cssq[2][128];
  int tid = threadIdx.x;
  {
    int sN, dN; float feat[32];
    edge_feat(x, he, ei, blockIdx.x*256 + tid, feat, sN, dN);
#pragma unroll
    for (int j4 = 0; j4 < 8; ++j4)
      *(float4*)&featl[tid*36 + j4*4] = *(float4*)&feat[j4*4];
  }
  int c = tid & 127, hh = tid >> 7;
  float w1c[32];
#pragma unroll
  for (int j = 0; j < 32; ++j) w1c[j] = w1[j*128 + c];
  float b1c = b1[c];
  __syncthreads();
  float s1 = 0.f, s2 = 0.f;
  for (int e = 0; e < 128; ++e) {
    const float* f = &featl[(hh*128 + e)*36];
    float acc = b1c;
#pragma unroll
    for (int j4 = 0; j4 < 8; ++j4) {
      float4 f4 = *(const float4*)&f[j4*4];
      acc += f4.x*w1c[j4*4] + f4.y*w1c[j4*4+1] + f4.z*w1c[j4*4+2] + f4.w*w1c[j4*4+3];
    }
    float t = leakyf(acc);
    s1 += t; s2 += t*t;
  }
  csum[hh][c] = s1; cssq[hh][c] = s2;
  __syncthreads();
  if (tid < 128) {
    atomicAdd(&stats[tid],     csum[0][tid] + csum[1][tid]);
    atomicAdd(&stats[128+tid], cssq[0][tid] + cssq[1][tid]);
  }
}

// ---------------- E2: finalize edge bn folded with emlp_w2 -> alpha,beta ----------------
__global__ void edge_finalize_kernel(const float* __restrict__ g_, const float* __restrict__ b_,
                                     const float* __restrict__ w2, const float* __restrict__ b2,
                                     float* __restrict__ ws)
{
  int side = blockIdx.y;
  float* stats = ws + (size_t)side*SS_ + STATS_OFF;
  __shared__ float red[128];
  int c = threadIdx.x;  // 128 threads
  const float invE = 1.f/(float)E_;
  float mean = stats[c]*invE;
  float var  = fmaxf(stats[128+c]*invE - mean*mean, 0.f);
  float scale = rsqrtf(var + 1e-5f) * g_[c];
  stats[256+c] = scale * w2[c];
  red[c] = (b_[c] - mean*scale) * w2[c];
  __syncthreads();
  for (int off = 64; off; off >>= 1) { if (c < off) red[c] += red[c+off]; __syncthreads(); }
  if (c == 0) stats[384] = red[0] + b2[0];
}

// ---------------- E3: w_e ----------------
__global__ __launch_bounds__(256)
void edge_w_kernel(const float* __restrict__ xl, const float* __restrict__ xr,
                   const float* __restrict__ hel, const float* __restrict__ her,
                   const int* __restrict__ ei1, const int* __restrict__ ei2,
                   const float* __restrict__ w1, const float* __restrict__ b1,
                   float* __restrict__ ws)
{
  int side = blockIdx.y;
  const float* x  = side ? xr  : xl;
  const float* he = side ? her : hel;
  const int*   ei = side ? ei2 : ei1;
  float* base = ws + (size_t)side*SS_;
  const float* stats = base + STATS_OFF;
  float* wbuf = base + W_OFF;
  float* deg  = base + DEG_OFF;
  __shared__ float w1t[128*32];
  __shared__ float b1l[128], all_[128];
  int tid = threadIdx.x;
  for (int i = tid; i < 4096; i += 256) {
    int j = i & 31, c = i >> 5;
    w1t[c*32 + j] = w1[j*128 + c];
  }
  if (tid < 128) { b1l[tid] = b1[tid]; all_[tid] = stats[256+tid]; }
  __syncthreads();
  int e = blockIdx.x*256 + tid;
  int sN, dN; float feat[32];
  edge_feat(x, he, ei, e, feat, sN, dN);
  float accw = stats[384];
  for (int c = 0; c < 128; ++c) {
    float acc = b1l[c];
#pragma unroll
    for (int j4 = 0; j4 < 8; ++j4) {
      float4 w4 = *(const float4*)&w1t[c*32 + j4*4];
      acc += feat[j4*4]*w4.x + feat[j4*4+1]*w4.y + feat[j4*4+2]*w4.z + feat[j4*4+3]*w4.w;
    }
    accw += leakyf(acc)*all_[c];
  }
  float w = fmaxf(accw, 0.f);
  wbuf[e] = w;
  atomicAdd(&deg[sN], w);
}

// ---------------- Bernstein propagation via Horner (6 matmuls) ----------------
__global__ __launch_bounds__(256)
void bern_horner_kernel(const float* __restrict__ hl_in, const float* __restrict__ hr_in,
                        const int* __restrict__ ei1, const int* __restrict__ ei2,
                        const float* __restrict__ bern_temp, float* __restrict__ ws)
{
  int side = blockIdx.y;
  int g  = blockIdx.x >> 2;
  int d0 = (blockIdx.x & 3) * 32;
  const float* h  = side ? hr_in : hl_in;
  const int*   ei = side ? ei2 : ei1;
  float* base = ws + (size_t)side*SS_;
  const float* wbuf = base + W_OFF;
  const float* deg  = base + DEG_OFF;
  float* hloc = base + HL_OFF;

  __shared__ float A[128*132];
  __shared__ float v[128*32];
  int tid = threadIdx.x;
  for (int i = tid; i < 128*132; i += 256) A[i] = 0.f;

  const float btab[7][7] = {
    { 1,  6, 15,  20, 15,  6,  1},
    { 1,  4,  5,   0, -5, -4, -1},
    { 1,  2, -1,  -4, -1,  2,  1},
    { 1,  0, -3,   0,  3,  0, -1},
    { 1, -2, -1,   4, -1, -2,  1},
    { 1, -4,  5,   0, -5,  4, -1},
    { 1, -6, 15, -20, 15, -6,  1}};
  const float comb6[7] = {1,6,15,20,15,6,1};
  float a[7];
#pragma unroll
  for (int m = 0; m < 7; ++m) a[m] = 0.f;
#pragma unroll
  for (int j = 0; j < 7; ++j) {
    float tj = fmaxf(bern_temp[j], 0.f) * comb6[j] * (1.f/64.f);
#pragma unroll
    for (int m = 0; m < 7; ++m) a[m] += tj * btab[j][m];
  }
  __syncthreads();

  int ebase = g*2048, nbase = g*128;
  for (int i = tid; i < 2048; i += 256) {
    int e = ebase + i;
    int sN = ei[e], dN = ei[E_ + e];
    float ds_ = deg[sN], dd_ = deg[dN];
    float aa = ds_ > 0.f ? rsqrtf(ds_ + 1e-12f) : 0.f;
    float bb = dd_ > 0.f ? rsqrtf(dd_ + 1e-12f) : 0.f;
    atomicAdd(&A[(dN - nbase)*132 + (sN - nbase)], wbuf[e]*aa*bb);
  }

  const int db = (tid & 7)*4;
  const int rb = (tid >> 3)*4;
  float hreg[4][4], r[4][4], t[4][4];
#pragma unroll
  for (int i = 0; i < 4; ++i) {
    float4 h4 = *(const float4*)&h[(size_t)(nbase + rb + i)*128 + d0 + db];
    hreg[i][0]=h4.x; hreg[i][1]=h4.y; hreg[i][2]=h4.z; hreg[i][3]=h4.w;
#pragma unroll
    for (int jj = 0; jj < 4; ++jj) r[i][jj] = a[6]*hreg[i][jj];
  }

  for (int step = 5; step >= 0; --step) {
    __syncthreads();
#pragma unroll
    for (int i = 0; i < 4; ++i)
      *(float4*)&v[(rb+i)*32 + db] = make_float4(r[i][0], r[i][1], r[i][2], r[i][3]);
    __syncthreads();
#pragma unroll
    for (int i = 0; i < 4; ++i)
#pragma unroll
      for (int jj = 0; jj < 4; ++jj) t[i][jj] = 0.f;
    for (int k = 0; k < 128; k += 4) {
      float4 V0 = *(const float4*)&v[(k+0)*32 + db];
      float4 V1 = *(const float4*)&v[(k+1)*32 + db];
      float4 V2 = *(const float4*)&v[(k+2)*32 + db];
      float4 V3 = *(const float4*)&v[(k+3)*32 + db];
#pragma unroll
      for (int i = 0; i < 4; ++i) {
        float4 A4 = *(const float4*)&A[(rb+i)*132 + k];
        t[i][0] += A4.x*V0.x + A4.y*V1.x + A4.z*V2.x + A4.w*V3.x;
        t[i][1] += A4.x*V0.y + A4.y*V1.y + A4.z*V2.y + A4.w*V3.y;
        t[i][2] += A4.x*V0.z + A4.y*V1.z + A4.z*V2.z + A4.w*V3.z;
        t[i][3] += A4.x*V0.w + A4.y*V1.w + A4.z*V2.w + A4.w*V3.w;
      }
    }
    float ak = a[step];
#pragma unroll
    for (int i = 0; i < 4; ++i)
#pragma unroll
      for (int jj = 0; jj < 4; ++jj) r[i][jj] = t[i][jj] + ak*hreg[i][jj];
  }

#pragma unroll
  for (int i = 0; i < 4; ++i)
    *(float4*)&hloc[(size_t)(nbase + rb + i)*128 + d0 + db] =
        make_float4(r[i][0], r[i][1], r[i][2], r[i][3]);
}

// ---------------- generic f32 GEMM, col-split for occupancy, grid.y = side ----------------
template<int K, int NC, int TC, int CSPLIT, int ACT, int GATHER, int SCATTER, int ADDC, int BIAS>
__global__ __launch_bounds__(256)
void gemm_kernel(const float* __restrict__ A0, const float* __restrict__ A1, int lda,
                 const float* __restrict__ W, const float* __restrict__ bias,
                 float* __restrict__ C0, float* __restrict__ C1, int ldc,
                 const int* __restrict__ idx0, const int* __restrict__ idx1,
                 const float* __restrict__ add0, const float* __restrict__ add1)
{
  int side = blockIdx.y;
  const float* A = side ? A1 : A0;
  float* C = side ? C1 : C0;
  const int* idx = side ? idx1 : idx0;
  const float* addsrc = side ? add1 : add0;
  constexpr int RPT = TC/8;
  constexpr int CLEN = NC/CSPLIT;
  __shared__ float Alds[32][K];
  __shared__ float Wlds[K][TC];
  const int tid = threadIdx.x;
  const int r0 = (blockIdx.x / CSPLIT) * 32;
  const int cbase = (blockIdx.x % CSPLIT) * CLEN;
  for (int i = tid*4; i < 32*K; i += 1024) {
    int r = i / K, k = i % K;
    int row = GATHER ? idx[r0 + r] : (r0 + r);
    *(float4*)&Alds[r][k] = *(const float4*)&A[(size_t)row*lda + k];
  }
  for (int c0 = cbase; c0 < cbase + CLEN; c0 += TC) {
    __syncthreads();
    for (int i = tid*4; i < K*TC; i += 1024) {
      int k = i / TC, c = i % TC;
      if (c0 + c < NC) *(float4*)&Wlds[k][c] = *(const float4*)&W[k*NC + c0 + c];
      else             *(float4*)&Wlds[k][c] = make_float4(0.f,0.f,0.f,0.f);
    }
    __syncthreads();
    const int cl = tid % TC;
    const int rsub = (tid / TC) * RPT;
    float accv[RPT];
#pragma unroll
    for (int j = 0; j < RPT; ++j) accv[j] = 0.f;
    for (int k = 0; k < K; k += 4) {
      float w0 = Wlds[k][cl], w1v = Wlds[k+1][cl], w2v = Wlds[k+2][cl], w3v = Wlds[k+3][cl];
#pragma unroll
      for (int j = 0; j < RPT; ++j) {
        float4 a4 = *(const float4*)&Alds[rsub+j][k];
        accv[j] += a4.x*w0 + a4.y*w1v + a4.z*w2v + a4.w*w3v;
      }
    }
    int c = c0 + cl;
    if (c < NC) {
#pragma unroll
      for (int j = 0; j < RPT; ++j) {
        int row  = r0 + rsub + j;
        int orow = SCATTER ? idx[row] : row;
        float vv = accv[j];
        if (BIAS)     vv += bias[c];
        if (ACT == 1) vv = leakyf(vv);
        if (ACT == 2) vv = fmaxf(vv, 0.f);
        if (ADDC)     vv += addsrc[(size_t)orow*ldc + c];
        C[(size_t)orow*ldc + c] = vv;
      }
    }
  }
}

// ---------------- qkv: 3 projections in one dispatch (grid.z = mat) ----------------
__global__ __launch_bounds__(256)
void qkv_kernel(const float* __restrict__ qw, const float* __restrict__ kw,
                const float* __restrict__ vw, float* __restrict__ ws)
{
  int side = blockIdx.y;
  int mat  = blockIdx.z;
  float* base = ws + (size_t)side*SS_;
  const float* A = base + HMID_OFF;
  const float* W = mat == 0 ? qw : (mat == 1 ? kw : vw);
  float* C = base + (mat == 0 ? XC_OFF : (mat == 1 ? DTB_OFF : YB_OFF));
  __shared__ float Alds[32][128];
  __shared__ float Wlds[128][64];
  const int tid = threadIdx.x;
  const int r0 = (blockIdx.x >> 1) * 32;
  const int c0 = (blockIdx.x & 1) * 64;
  for (int i = tid*4; i < 32*128; i += 1024)
    *(float4*)&Alds[i>>7][i&127] = *(const float4*)&A[(size_t)(r0 + (i>>7))*128 + (i&127)];
  for (int i = tid*4; i < 128*64; i += 1024)
    *(float4*)&Wlds[i>>6][i&63] = *(const float4*)&W[(i>>6)*128 + c0 + (i&63)];
  __syncthreads();
  const int cl = tid & 63;
  const int rsub = (tid >> 6) * 8;
  float accv[8];
#pragma unroll
  for (int j = 0; j < 8; ++j) accv[j] = 0.f;
  for (int k = 0; k < 128; k += 4) {
    float w0 = Wlds[k][cl], w1v = Wlds[k+1][cl], w2v = Wlds[k+2][cl], w3v = Wlds[k+3][cl];
#pragma unroll
    for (int j = 0; j < 8; ++j) {
      float4 a4 = *(const float4*)&Alds[rsub+j][k];
      accv[j] += a4.x*w0 + a4.y*w1v + a4.z*w2v + a4.w*w3v;
    }
  }
#pragma unroll
  for (int j = 0; j < 8; ++j) {
    float vv = accv[j];
    if (mat < 2) vv = leakyf(vv);
    C[(size_t)(r0 + rsub + j)*128 + c0 + cl] = vv;
  }
}

// ---------------- mamba: causal depthwise conv (DCONV=4) + silu ----------------
__global__ __launch_bounds__(256)
void conv_kernel(const float* __restrict__ cw, const float* __restrict__ cb, float* __restrict__ ws)
{
  int side = blockIdx.y;
  float* base = ws + (size_t)side*SS_;
  const float* xz = base + XZ_OFF;
  float* xc = base + XC_OFF;
  int i = blockIdx.x*256 + threadIdx.x;
  int j = i >> 7, d = i & 127;
  int l = j & 127;
  float a = cb[d];
#pragma unroll
  for (int k = 0; k < 4; ++k) {
    int ll = l - 3 + k;
    if (ll >= 0) a += xz[(size_t)(j-3+k)*256 + d] * cw[d*4 + k];
  }
  xc[i] = siluf(a);
}

// ---------------- mamba scan: fused dt(softplus) + 128-step recurrence + gate ----------------
// block = (group g, 16-dim slice dg, side); all operands staged in LDS once.
__global__ __launch_bounds__(256)
void scan_kernel(const float* __restrict__ A_log, const float* __restrict__ Dp,
                 const float* __restrict__ dtw, const float* __restrict__ dtbias,
                 float* __restrict__ ws)
{
  int side = blockIdx.z;
  int g  = blockIdx.x;
  int d0 = blockIdx.y * 16;
  float* base = ws + (size_t)side*SS_;
  const float* dbl = base + DBL_OFF;
  const float* xcb = base + XC_OFF;
  float* xz = base + XZ_OFF;

  __shared__ float ldbl[128][40];   // dt-in(8) | B(16) | C(16)
  __shared__ float lxc[128][16];
  __shared__ float ldt[128][16];
  __shared__ float lz[128][16];
  __shared__ float ly[128][16];
  __shared__ float ltw[8][16];
  __shared__ float ltb[16];

  int tid = threadIdx.x;
  int rowbase = g*128;
  if (tid < 128)      ltw[tid>>4][tid&15] = dtw[(tid>>4)*128 + d0 + (tid&15)];
  else if (tid < 144) ltb[tid-128] = dtbias[d0 + (tid-128)];
  for (int i = tid; i < 128*40; i += 256)
    ((float*)ldbl)[i] = dbl[(size_t)rowbase*40 + i];
  for (int i = tid; i < 2048; i += 256) {
    int l = i >> 4, dd = i & 15;
    lxc[l][dd] = xcb[(size_t)(rowbase+l)*128 + d0 + dd];
    lz[l][dd]  = xz[(size_t)(rowbase+l)*256 + 128 + d0 + dd];
  }
  __syncthreads();
  // dt = softplus(dbl[:, :8] @ dtw + dtb)  — once per (l,d)
  for (int i = tid; i < 2048; i += 256) {
    int l = i >> 4, dd = i & 15;
    float a = ltb[dd];
#pragma unroll
    for (int k = 0; k < 8; ++k) a += ldbl[l][k]*ltw[k][dd];
    ldt[l][dd] = a > 20.f ? a : log1pf(expf(a));
  }
  __syncthreads();

  int s = tid & 15, dl = (tid >> 4) & 15;
  float Ac  = -expf(A_log[(d0+dl)*16 + s]);
  float dpv = Dp[d0+dl];
  float hsv = 0.f;
  for (int l = 0; l < 128; ++l) {
    float dtv = ldt[l][dl];      // broadcast across s
    float xcv = lxc[l][dl];
    float Bv  = ldbl[l][8+s];
    float Cv  = ldbl[l][24+s];
    hsv = expf(dtv*Ac)*hsv + (dtv*xcv)*Bv;
    float val = hsv*Cv;
    val += __shfl_xor(val, 1, 16);
    val += __shfl_xor(val, 2, 16);
    val += __shfl_xor(val, 4, 16);
    val += __shfl_xor(val, 8, 16);
    if (s == 0) ly[l][dl] = val + xcv*dpv;
  }
  __syncthreads();
  // gate: xz[:, :128] = y * silu(z)
  for (int i = tid; i < 2048; i += 256) {
    int l = i >> 4, dd = i & 15;
    float y = ly[l][dd];
    float z = lz[l][dd];
    xz[(size_t)(rowbase+l)*256 + d0 + dd] = y * siluf(z);
  }
}

// ---------------- column stats ----------------
__global__ __launch_bounds__(256)
void stats_kernel(const float* __restrict__ hl_in, const float* __restrict__ hr_in,
                  float* __restrict__ ws, int mode, int statsoff)
{
  int side = blockIdx.y;
  float* base = ws + (size_t)side*SS_;
  const float* h    = side ? hr_in : hl_in;
  const float* hloc = base + HL_OFF;
  const float* ha   = base + HA_OFF;
  float* x1 = base + X1_OFF;
  float* stats = base + STATS_OFF + statsoff;
  int tid = threadIdx.x;
  int c = tid & 127;
  float s1 = 0.f, s2 = 0.f;
  for (int it = 0; it < 16; ++it) {
    int r = blockIdx.x*32 + (tid >> 7) + it*2;
    size_t i = (size_t)r*128 + c;
    float v;
    if (mode == 0) { v = h[i] + hloc[i] + ha[i]; x1[i] = v; }
    else           { v = ha[i]; }
    s1 += v; s2 += v*v;
  }
  __shared__ float red[256];
  red[tid] = s1; __syncthreads();
  if (tid < 128) atomicAdd(&stats[tid], red[tid] + red[tid+128]);
  __syncthreads();
  red[tid] = s2; __syncthreads();
  if (tid < 128) atomicAdd(&stats[128+tid], red[tid] + red[tid+128]);
}

__global__ void bn_finalize_kernel(const float* __restrict__ g_, const float* __restrict__ b_,
                                   float* __restrict__ ws, int statsoff, float invM)
{
  int side = blockIdx.y;
  float* stats = ws + (size_t)side*SS_ + STATS_OFF + statsoff;
  int c = threadIdx.x;   // 128 threads
  float mean = stats[c]*invM;
  float var  = fmaxf(stats[128+c]*invM - mean*mean, 0.f);
  float scale = rsqrtf(var + 1e-5f) * g_[c];
  stats[256+c] = scale;
  stats[384+c] = b_[c] - mean*scale;
}

__global__ __launch_bounds__(256)
void bn_apply_kernel(float* __restrict__ ws, float* __restrict__ dout,
                     int srcoff, int dstoff, int statsoff, int to_dout)
{
  int side = blockIdx.y;
  float* base = ws + (size_t)side*SS_;
  const float* src = base + srcoff;
  const float* stats = base + STATS_OFF + statsoff;
  float* dst = to_dout ? (dout + (size_t)side*ND_) : (base + dstoff);
  size_t i = (size_t)blockIdx.x*256 + threadIdx.x;
  int c = (int)(i & 127);
  dst[i] = src[i]*stats[256+c] + stats[384+c];
}

// ---------------- cross attention ----------------
__global__ __launch_bounds__(256)
void attn_kernel(float* __restrict__ ws)
{
  int dir = blockIdx.z;
  int g   = blockIdx.x;
  int rt  = blockIdx.y;
  float* baseq = ws + (size_t)dir*SS_;
  float* basek = ws + (size_t)(1-dir)*SS_;
  const float* qb = baseq + XC_OFF;
  const float* kb = basek + DTB_OFF;
  const float* vb = basek + YB_OFF;
  const float* hm = baseq + HMID_OFF;
  float* h2 = baseq + X1_OFF;
  __shared__ float kT[128*129];
  __shared__ float sp[32*128];
  int tid = threadIdx.x;
  for (int i = tid; i < 16384; i += 256) {
    int n = i >> 7, d = i & 127;
    kT[d*129 + n] = kb[(size_t)(g*128+n)*128 + d];
  }
  __syncthreads();
  int wv = tid >> 6, lane = tid & 63;
  for (int rl = wv; rl < 32; rl += 4) {
    int r = g*128 + rt*32 + rl;
    const float* qrow = qb + (size_t)r*128;
    float a0 = 0.f, a1 = 0.f;
    for (int d = 0; d < 128; ++d) {
      float qv = qrow[d];
      a0 += qv * kT[d*129 + lane];
      a1 += qv * kT[d*129 + 64 + lane];
    }
    float m = fmaxf(a0, a1);
#pragma unroll
    for (int off = 32; off; off >>= 1) m = fmaxf(m, __shfl_xor(m, off));
    float p0 = expf(a0 - m), p1 = expf(a1 - m);
    float ssum = p0 + p1;
#pragma unroll
    for (int off = 32; off; off >>= 1) ssum += __shfl_xor(ssum, off);
    float inv = 1.f/ssum;
    sp[rl*128 + lane]      = p0*inv;
    sp[rl*128 + 64 + lane] = p1*inv;
  }
  __syncthreads();
  for (int i = tid; i < 16384; i += 256) {
    int n = i >> 7, d = i & 127;
    kT[n*129 + d] = vb[(size_t)(g*128+n)*128 + d];
  }
  __syncthreads();
  for (int rl = wv; rl < 32; rl += 4) {
    int r = g*128 + rt*32 + rl;
    float a0 = 0.f, a1 = 0.f;
    const float* prow = sp + rl*128;
    for (int c = 0; c < 128; ++c) {
      float p = prow[c];
      a0 += p * kT[c*129 + lane];
      a1 += p * kT[c*129 + 64 + lane];
    }
    size_t o = (size_t)r*128;
    h2[o + lane]      = hm[o + lane]      + a0;
    h2[o + 64 + lane] = hm[o + 64 + lane] + a1;
  }
}

// ---------------- launch ----------------
extern "C" void kernel_launch(void* const* d_in, const int* in_sizes, int n_in,
                              void* d_out, int out_size, void* d_ws, size_t ws_size,
                              hipStream_t stream)
{
  const float* h_lig     = (const float*)d_in[0];
  const float* h_rec     = (const float*)d_in[1];
  const float* x_lig     = (const float*)d_in[2];
  const float* x_rec     = (const float*)d_in[3];
  const float* he_1      = (const float*)d_in[4];
  const float* he_2      = (const float*)d_in[5];
  const float* emlp_w1   = (const float*)d_in[6];
  const float* emlp_b1   = (const float*)d_in[7];
  const float* emlp_bn_g = (const float*)d_in[8];
  const float* emlp_bn_b = (const float*)d_in[9];
  const float* emlp_w2   = (const float*)d_in[10];
  const float* emlp_b2   = (const float*)d_in[11];
  const float* bern_temp = (const float*)d_in[12];
  const float* m_in_w    = (const float*)d_in[13];
  const float* m_conv_w  = (const float*)d_in[14];
  const float* m_conv_b  = (const float*)d_in[15];
  const float* m_xproj_w = (const float*)d_in[16];
  const float* m_dt_w    = (const float*)d_in[17];
  const float* m_dt_b    = (const float*)d_in[18];
  const float* m_A_log   = (const float*)d_in[19];
  const float* m_D       = (const float*)d_in[20];
  const float* m_out_w   = (const float*)d_in[21];
  const float* q_w       = (const float*)d_in[22];
  const float* k_w       = (const float*)d_in[23];
  const float* v_w       = (const float*)d_in[24];
  const float* bn1_g     = (const float*)d_in[25];
  const float* bn1_b     = (const float*)d_in[26];
  const float* bn2_g     = (const float*)d_in[27];
  const float* bn2_b     = (const float*)d_in[28];
  const float* ff_w1     = (const float*)d_in[29];
  const float* ff_b1     = (const float*)d_in[30];
  const float* ff_w2     = (const float*)d_in[31];
  const float* ff_b2     = (const float*)d_in[32];
  const int*   ei1       = (const int*)d_in[33];
  const int*   ei2       = (const int*)d_in[34];
  const int*   perm1     = (const int*)d_in[37];
  const int*   perm2     = (const int*)d_in[38];

  float* ws   = (float*)d_ws;
  float* dout = (float*)d_out;

#define B0(off) (ws + (size_t)(off))
#define B1(off) (ws + SS_ + (size_t)(off))

  for (int s = 0; s < 2; ++s)
    hipMemsetAsync((char*)d_ws + ((size_t)s*SS_ + DEG_OFF)*sizeof(float), 0,
                   (N_ + 2048)*sizeof(float), stream);

  // edge weights
  edge_stats_kernel<<<dim3(256,2), 256, 0, stream>>>(x_lig,x_rec,he_1,he_2,ei1,ei2,emlp_w1,emlp_b1,ws);
  edge_finalize_kernel<<<dim3(1,2), 128, 0, stream>>>(emlp_bn_g,emlp_bn_b,emlp_w2,emlp_b2,ws);
  edge_w_kernel<<<dim3(256,2), 256, 0, stream>>>(x_lig,x_rec,he_1,he_2,ei1,ei2,emlp_w1,emlp_b1,ws);

  // bernstein propagation (Horner, 6 matmuls)
  bern_horner_kernel<<<dim3(G_*4,2), 256, 0, stream>>>(h_lig,h_rec,ei1,ei2,bern_temp,ws);

  // mamba
  gemm_kernel<128,256,64,4,0,1,0,0,0><<<dim3(512,2),256,0,stream>>>(
      h_lig,h_rec,128, m_in_w,nullptr, B0(XZ_OFF),B1(XZ_OFF),256, perm1,perm2, nullptr,nullptr);
  conv_kernel<<<dim3(2048,2), 256, 0, stream>>>(m_conv_w,m_conv_b,ws);
  gemm_kernel<128,40,64,1,0,0,0,0,0><<<dim3(128,2),256,0,stream>>>(
      B0(XC_OFF),B1(XC_OFF),128, m_xproj_w,nullptr, B0(DBL_OFF),B1(DBL_OFF),40, nullptr,nullptr, nullptr,nullptr);
  scan_kernel<<<dim3(32,8,2), 256, 0, stream>>>(m_A_log,m_D,m_dt_w,m_dt_b,ws);
  gemm_kernel<128,128,64,2,0,0,1,0,0><<<dim3(256,2),256,0,stream>>>(
      B0(XZ_OFF),B1(XZ_OFF),256, m_out_w,nullptr, B0(HA_OFF),B1(HA_OFF),128, perm1,perm2, nullptr,nullptr);

  // bn1( h + h_local + ha )
  stats_kernel<<<dim3(128,2), 256, 0, stream>>>(h_lig,h_rec,ws,0,512);
  bn_finalize_kernel<<<dim3(1,2), 128, 0, stream>>>(bn1_g,bn1_b,ws,512,1.f/(float)N_);
  bn_apply_kernel<<<dim3(2048,2), 256, 0, stream>>>(ws,dout,X1_OFF,HMID_OFF,512,0);

  // q,k,v projections in one dispatch
  qkv_kernel<<<dim3(256,2,3), 256, 0, stream>>>(q_w,k_w,v_w,ws);
  attn_kernel<<<dim3(32,4,2), 256, 0, stream>>>(ws);

  // ffn + bn2
  gemm_kernel<128,256,64,4,2,0,0,0,1><<<dim3(512,2),256,0,stream>>>(
      B0(X1_OFF),B1(X1_OFF),128, ff_w1,ff_b1, B0(XZ_OFF),B1(XZ_OFF),256, nullptr,nullptr, nullptr,nullptr);
  gemm_kernel<256,128,32,4,0,0,0,1,1><<<dim3(512,2),256,0,stream>>>(
      B0(XZ_OFF),B1(XZ_OFF),256, ff_w2,ff_b2, B0(HA_OFF),B1(HA_OFF),128, nullptr,nullptr, B0(X1_OFF),B1(X1_OFF));
  stats_kernel<<<dim3(128,2), 256, 0, stream>>>(h_lig,h_rec,ws,1,1024);
  bn_finalize_kernel<<<dim3(1,2), 128, 0, stream>>>(bn2_g,bn2_b,ws,1024,1.f/(float)N_);
  bn_apply_kernel<<<dim3(2048,2), 256, 0, stream>>>(ws,dout,HA_OFF,0,1024,1);
}